// Round 20
// baseline (128.766 us; speedup 1.0000x reference)
//
#include <hip/hip_runtime.h>
#include <stdint.h>
#include <stddef.h>

#define NB 16
#define NC 512
#define NT 1024
#define NHEAD 8
#define NOC 1536

typedef float f32x4 __attribute__((ext_vector_type(4)));
typedef short s16x8 __attribute__((ext_vector_type(8)));
typedef short s16x4 __attribute__((ext_vector_type(4)));
typedef unsigned int u32x2 __attribute__((ext_vector_type(2)));

#define AS1 __attribute__((address_space(1)))
#define AS3 __attribute__((address_space(3)))

static __device__ __forceinline__ unsigned short f2bf(float f) {
  union { float fv; unsigned int u; } v; v.fv = f;
  return (unsigned short)((v.u + 0x7fffu + ((v.u >> 16) & 1u)) >> 16);
}

// v_cvt_pk_bf16_f32: dst.lo16 = bf16(lo), dst.hi16 = bf16(hi)
static __device__ __forceinline__ unsigned int cvtpk(float lo, float hi) {
  unsigned int r;
  asm("v_cvt_pk_bf16_f32 %0, %1, %2" : "=v"(r) : "v"(lo), "v"(hi));
  return r;
}

// v_exp_f32: D = 2^S0 (gfx950 ISA §3) — exp2-domain softmax
static __device__ __forceinline__ float exp2_hw(float x) {
  float r;
  asm("v_exp_f32 %0, %1" : "=v"(r) : "v"(x));
  return r;
}

// ---------------- kernel 0: weights fp32 -> bf16 ----------------
__global__ void k_convert(const float* __restrict__ wq, const float* __restrict__ wp,
                          unsigned short* __restrict__ wqb, unsigned short* __restrict__ wpb) {
  int i = blockIdx.x * 256 + threadIdx.x;
  int step = gridDim.x * 256;
  for (int idx = i; idx < NOC * NC; idx += step) wqb[idx] = f2bf(wq[idx]);
  for (int idx = i; idx < NC * NC; idx += step) wpb[idx] = f2bf(wp[idx]);
}

// ---------------- kernel 1: groupnorm stats -> per (b,c) affine ----------------
__global__ __launch_bounds__(256) void k_gnstats(const float* __restrict__ x,
    const float* __restrict__ gsc, const float* __restrict__ gbi,
    float* __restrict__ affA, float* __restrict__ affB) {
  int b = blockIdx.x >> 5, g = blockIdx.x & 31;
  const f32x4* p4 = (const f32x4*)(x + (size_t)(b * NC + g * 16) * NT);
  float s = 0.f, ss = 0.f;
  for (int i = threadIdx.x; i < 4096; i += 256) {
    f32x4 v = p4[i];
    s += v[0] + v[1] + v[2] + v[3];
    ss += v[0] * v[0] + v[1] * v[1] + v[2] * v[2] + v[3] * v[3];
  }
#pragma unroll
  for (int off = 32; off > 0; off >>= 1) { s += __shfl_down(s, off); ss += __shfl_down(ss, off); }
  __shared__ float red[4][2];
  if ((threadIdx.x & 63) == 0) { red[threadIdx.x >> 6][0] = s; red[threadIdx.x >> 6][1] = ss; }
  __syncthreads();
  if (threadIdx.x < 16) {
    float st = red[0][0] + red[1][0] + red[2][0] + red[3][0];
    float sst = red[0][1] + red[1][1] + red[2][1] + red[3][1];
    float mean = st * (1.f / 16384.f);
    float var = sst * (1.f / 16384.f) - mean * mean;
    float rstd = rsqrtf(var + 1e-5f);
    int c = g * 16 + threadIdx.x;
    float a = rstd * gsc[c];
    affA[b * NC + c] = a;
    affB[b * NC + c] = gbi[c] - mean * a;
  }
}

// ---------------- kernel 2: normalize + transpose -> xt[b][t][c] bf16 ----------------
__global__ __launch_bounds__(256) void k_norm_t(const float* __restrict__ x,
    const float* __restrict__ affA, const float* __restrict__ affB,
    unsigned short* __restrict__ xt) {
  __shared__ float sm[64][65];
  int bx = blockIdx.x;
  int tt = bx & 15, ct = (bx >> 4) & 7, b = bx >> 7;
  int c0 = ct * 64, t0 = tt * 64;
  int tid = threadIdx.x;
#pragma unroll
  for (int it = 0; it < 4; it++) {
    int row = (tid >> 4) + it * 16;
    int col = (tid & 15) * 4;
    int c = c0 + row;
    f32x4 v = *(const f32x4*)(x + (size_t)(b * NC + c) * NT + t0 + col);
    float a = affA[b * NC + c], bb = affB[b * NC + c];
    sm[row][col + 0] = v[0] * a + bb;
    sm[row][col + 1] = v[1] * a + bb;
    sm[row][col + 2] = v[2] * a + bb;
    sm[row][col + 3] = v[3] * a + bb;
  }
  __syncthreads();
#pragma unroll
  for (int it = 0; it < 2; it++) {
    int t = (tid >> 3) + it * 32;
    int cb = (tid & 7) * 8;
    s16x8 o;
#pragma unroll
    for (int j = 0; j < 8; j++) o[j] = (short)f2bf(sm[cb + j][t]);
    *(s16x8*)(xt + (size_t)(b * NT + t0 + t) * NC + c0 + cb) = o;
  }
}

// -------- kernel 3: QKV GEMM (triple-buffer, 1 barrier/K-step; Tr aliased post-loop) --------
__global__ __launch_bounds__(256) void k_qkv(const unsigned short* __restrict__ wqb,
    const unsigned short* __restrict__ xt, const float* __restrict__ bqkv,
    unsigned short* __restrict__ qt, unsigned short* __restrict__ ktb,
    unsigned short* __restrict__ vvb) {
  __shared__ char LB[49152];   // 3 × [A:8K|B:8K]; epilogue reuses first 32K as per-wave Tr
  int n0 = blockIdx.x * 128;
  int m0 = blockIdx.y * 128;
  int b = blockIdx.z;
  int tid = threadIdx.x, lane = tid & 63, wid = tid >> 6;
  int wr = wid >> 1, wc = wid & 1;
  int arow = lane >> 2, acol = (lane & 3) * 8;
  f32x4 acc[4][4] = {};
  // prologue: stage ks=0 -> buf0, ks=1 -> buf1
#pragma unroll
  for (int t0 = 0; t0 < 2; t0++) {
#pragma unroll
    for (int cc = 0; cc < 2; cc++) {
      int ci = wid * 2 + cc;
      const unsigned short* ga = wqb + (size_t)(m0 + ci * 16 + arow) * NC + t0 * 32 + acol;
      __builtin_amdgcn_global_load_lds((const AS1 unsigned int*)ga,
                                       (AS3 unsigned int*)(LB + t0 * 16384 + ci * 1024), 16, 0, 0);
      const unsigned short* gb = xt + (size_t)(b * NT + n0 + ci * 16 + arow) * NC + t0 * 32 + acol;
      __builtin_amdgcn_global_load_lds((const AS1 unsigned int*)gb,
                                       (AS3 unsigned int*)(LB + t0 * 16384 + 8192 + ci * 1024), 16, 0, 0);
    }
  }
  for (int ks = 0; ks < 16; ks++) {
    char* Ac = LB + (ks % 3) * 16384;
    char* Bc = Ac + 8192;
    if (ks < 14) {
      asm volatile("s_waitcnt vmcnt(4)" ::: "memory");   // tile ks landed (ks+1 in flight)
    } else {
      asm volatile("s_waitcnt vmcnt(0)" ::: "memory");
    }
    __builtin_amdgcn_s_barrier();
    __builtin_amdgcn_sched_barrier(0);
    if (ks + 2 < 16) {
      // prefetch tile ks+2 into buf[(ks+2)%3] — its last readers passed the barrier above
      int k0n = (ks + 2) * 32;
      char* An = LB + ((ks + 2) % 3) * 16384;
#pragma unroll
      for (int cc = 0; cc < 2; cc++) {
        int ci = wid * 2 + cc;
        const unsigned short* ga = wqb + (size_t)(m0 + ci * 16 + arow) * NC + k0n + acol;
        __builtin_amdgcn_global_load_lds((const AS1 unsigned int*)ga,
                                         (AS3 unsigned int*)(An + ci * 1024), 16, 0, 0);
        const unsigned short* gb = xt + (size_t)(b * NT + n0 + ci * 16 + arow) * NC + k0n + acol;
        __builtin_amdgcn_global_load_lds((const AS1 unsigned int*)gb,
                                         (AS3 unsigned int*)(An + 8192 + ci * 1024), 16, 0, 0);
      }
    }
    s16x8 af[4], bfv[4];
#pragma unroll
    for (int mi = 0; mi < 4; mi++)
      af[mi] = *(const s16x8*)(Ac + ((wr * 64 + mi * 16 + (lane & 15)) * 32 + (lane >> 4) * 8) * 2);
#pragma unroll
    for (int ni = 0; ni < 4; ni++)
      bfv[ni] = *(const s16x8*)(Bc + ((wc * 64 + ni * 16 + (lane & 15)) * 32 + (lane >> 4) * 8) * 2);
#pragma unroll
    for (int mi = 0; mi < 4; mi++)
#pragma unroll
      for (int ni = 0; ni < 4; ni++)
        acc[mi][ni] = __builtin_amdgcn_mfma_f32_16x16x32_bf16(af[mi], bfv[ni], acc[mi][ni], 0, 0, 0);
  }
  __syncthreads();   // all waves done with LDS buffers before Tr aliasing
  // epilogue: per-wave private Tr region aliased onto the dead buffers
  char* tr = LB + wid * 8192;
  int o064 = m0 + wr * 64;
  int blk = (o064 >> 6) % 3;  // 0=q 1=k 2=v
  int head = o064 / 192;
  int bh = b * NHEAD + head;
  int n0w = n0 + wc * 64;
  // 64^-0.25 * sqrt(log2(e)) folded into q and k (softmax runs in exp2 domain)
  const float scale = 0.42466090014400953f;
  if (blk < 2) {
    // token-major [t][ch] via swizzled LDS transpose
#pragma unroll
    for (int mi = 0; mi < 4; mi++) {
      int o_loc = mi * 16 + (lane >> 4) * 4;
      float b0 = bqkv[o064 + o_loc + 0], b1 = bqkv[o064 + o_loc + 1];
      float b2 = bqkv[o064 + o_loc + 2], b3 = bqkv[o064 + o_loc + 3];
#pragma unroll
      for (int ni = 0; ni < 4; ni++) {
        int t_loc = ni * 16 + (lane & 15);
        s16x4 pk;
        pk[0] = (short)f2bf((acc[mi][ni][0] + b0) * scale);
        pk[1] = (short)f2bf((acc[mi][ni][1] + b1) * scale);
        pk[2] = (short)f2bf((acc[mi][ni][2] + b2) * scale);
        pk[3] = (short)f2bf((acc[mi][ni][3] + b3) * scale);
        *(s16x4*)(tr + t_loc * 128 + ((o_loc * 2) ^ ((t_loc & 7) << 4))) = pk;
      }
    }
    unsigned short* outp = (blk == 0) ? qt : ktb;
#pragma unroll
    for (int pass = 0; pass < 8; pass++) {
      int t = pass * 8 + (lane >> 3);
      int cb = (lane & 7) * 16;
      s16x8 v = *(const s16x8*)(tr + t * 128 + (cb ^ ((t & 7) << 4)));
      *(s16x8*)(outp + (size_t)(bh * NT + n0w + t) * 64 + (cb >> 1)) = v;
    }
  } else {
    // v channel-major [ch][t], C-tile is already row-major in o
#pragma unroll
    for (int mi = 0; mi < 4; mi++) {
#pragma unroll
      for (int ni = 0; ni < 4; ni++) {
        int t_loc = ni * 16 + (lane & 15);
#pragma unroll
        for (int r = 0; r < 4; r++) {
          int o_loc = mi * 16 + (lane >> 4) * 4 + r;
          *(unsigned short*)(tr + o_loc * 128 + t_loc * 2) =
              f2bf(acc[mi][ni][r] + bqkv[o064 + o_loc]);
        }
      }
    }
#pragma unroll
    for (int pass = 0; pass < 8; pass++) {
      int o = pass * 8 + (lane >> 3);
      int tb = (lane & 7) * 16;
      s16x8 v = *(const s16x8*)(tr + o * 128 + tb);
      *(s16x8*)(vvb + (size_t)(bh * 64 + o) * NT + n0w + (tb >> 1)) = v;
    }
  }
}

// ---- kernel 4: flash attention (triple-buffer K/V, 1 barrier/iter, MFMA row-sums) ----
__global__ __launch_bounds__(512, 4) void k_attn(const unsigned short* __restrict__ qt,
    const unsigned short* __restrict__ ktb, const unsigned short* __restrict__ vvb,
    unsigned short* __restrict__ rt) {
  __shared__ char Kl[3][8192];        // [64 tk][64 ch] bf16, row-swizzled image, triple-buffered
  __shared__ char Vl[3][8192];        // [64 ch][64 tk] bf16, row-swizzled image, triple-buffered
  __shared__ char Pl[8][4096];        // per-wave [32 q][64 tk] bf16, row-swizzled
  int qt0 = blockIdx.x * 256;
  int bh = blockIdx.y;
  int b = bh >> 3, head = bh & 7;
  int tid = threadIdx.x, lane = tid & 63, wid = tid >> 6;
  int hi = lane >> 4, lo = lane & 15;
  int q0 = qt0 + wid * 32;
  // Q as B-fragments: aq[mi][ko] = Q[q0+mi*16+lo][ko*32 + hi*8 .. +8]
  s16x8 aq[2][2];
#pragma unroll
  for (int mi = 0; mi < 2; mi++)
#pragma unroll
    for (int ko = 0; ko < 2; ko++)
      aq[mi][ko] = *(const s16x8*)(qt + (size_t)(bh * NT + q0 + mi * 16 + lo) * 64 +
                                   ko * 32 + hi * 8);
  f32x4 oacc[2][4] = {};              // O^T: col q = lo, row d = hi*4+r (per mi, dm)
  f32x4 lacc[2] = {};                 // row-sum accumulator via mfma(ones, P): all rows = l[q]
  float mrun[2] = {-1e30f, -1e30f};
  s16x8 ones;
#pragma unroll
  for (int j = 0; j < 8; j++) ones[j] = (short)0x3F80;   // bf16 1.0
  char* pl = (char*)Pl[wid];
  // async-staging coords: wave wid covers rows wid*8..wid*8+7 (1 KB) of each 8 KB tile;
  // LDS dest linear, swizzle folded into the per-lane GLOBAL address (involution).
  int srow = (wid << 3) + (lane >> 3);
  int soff = ((lane & 7) << 4) ^ ((srow & 7) << 4);
  const char* kb = (const char*)ktb + ((size_t)bh * NT + srow) * 128 + soff;
  const char* vb = (const char*)vvb + ((size_t)(bh * 64 + srow)) * 2048 + soff;
  // prologue: issue tiles 0,1 into bufs 0,1
#pragma unroll
  for (int t0 = 0; t0 < 2; t0++) {
    __builtin_amdgcn_global_load_lds((const AS1 unsigned int*)(kb + (size_t)t0 * 8192),
                                     (AS3 unsigned int*)(Kl[t0] + (wid << 10)), 16, 0, 0);
    __builtin_amdgcn_global_load_lds((const AS1 unsigned int*)(vb + (size_t)t0 * 128),
                                     (AS3 unsigned int*)(Vl[t0] + (wid << 10)), 16, 0, 0);
  }
  for (int kv = 0; kv < 16; kv++) {
    int cur = kv % 3;
    if (kv < 14) {
      asm volatile("s_waitcnt vmcnt(2)" ::: "memory");   // tile kv landed (kv+1 in flight)
    } else {
      asm volatile("s_waitcnt vmcnt(0)" ::: "memory");
    }
    __builtin_amdgcn_s_barrier();
    __builtin_amdgcn_sched_barrier(0);
    if (kv + 2 < 16) {
      // prefetch tile kv+2 into buf[(kv+2)%3] — its last readers passed the barrier above
      int nb = (kv + 2) % 3;
      __builtin_amdgcn_global_load_lds((const AS1 unsigned int*)(kb + (size_t)(kv + 2) * 8192),
                                       (AS3 unsigned int*)(Kl[nb] + (wid << 10)), 16, 0, 0);
      __builtin_amdgcn_global_load_lds((const AS1 unsigned int*)(vb + (size_t)(kv + 2) * 128),
                                       (AS3 unsigned int*)(Vl[nb] + (wid << 10)), 16, 0, 0);
    }
    // S^T = K * Q^T : sc[mi][ni] holds S[tk=ni*16+hi*4+r][q=mi*16+lo], exp2 domain
    f32x4 sc[2][4] = {};
#pragma unroll
    for (int ni = 0; ni < 4; ni++) {
      int tkr = ni * 16 + lo;
#pragma unroll
      for (int ko = 0; ko < 2; ko++) {
        s16x8 kf = *(const s16x8*)(Kl[cur] + tkr * 128 + ((ko * 64 + hi * 16) ^ ((tkr & 7) << 4)));
        sc[0][ni] = __builtin_amdgcn_mfma_f32_16x16x32_bf16(kf, aq[0][ko], sc[0][ni], 0, 0, 0);
        sc[1][ni] = __builtin_amdgcn_mfma_f32_16x16x32_bf16(kf, aq[1][ko], sc[1][ni], 0, 0, 0);
      }
    }
    // online softmax (exp2 domain), defer-max (THR=8): per q = lo, + 2 shfl over hi
#pragma unroll
    for (int mi = 0; mi < 2; mi++) {
      float a0 = fmaxf(fmaxf(sc[mi][0][0], sc[mi][0][1]), fmaxf(sc[mi][0][2], sc[mi][0][3]));
      float a1 = fmaxf(fmaxf(sc[mi][1][0], sc[mi][1][1]), fmaxf(sc[mi][1][2], sc[mi][1][3]));
      float a2 = fmaxf(fmaxf(sc[mi][2][0], sc[mi][2][1]), fmaxf(sc[mi][2][2], sc[mi][2][3]));
      float a3 = fmaxf(fmaxf(sc[mi][3][0], sc[mi][3][1]), fmaxf(sc[mi][3][2], sc[mi][3][3]));
      float tm = fmaxf(fmaxf(a0, a1), fmaxf(a2, a3));
      tm = fmaxf(tm, __shfl_xor(tm, 16));
      tm = fmaxf(tm, __shfl_xor(tm, 32));
      int resc = __any(tm > mrun[mi] + 8.f);   // wave-uniform
      float mnew = mrun[mi];
      if (resc) {
        mnew = fmaxf(mrun[mi], tm);
        float fac = exp2_hw(mrun[mi] - mnew);
        mrun[mi] = mnew;
#pragma unroll
        for (int dm = 0; dm < 4; dm++)
#pragma unroll
          for (int r = 0; r < 4; r++) oacc[mi][dm][r] *= fac;
#pragma unroll
        for (int r = 0; r < 4; r++) lacc[mi][r] *= fac;
      }
#pragma unroll
      for (int ni = 0; ni < 4; ni++)
#pragma unroll
        for (int r = 0; r < 4; r++) sc[mi][ni][r] = exp2_hw(sc[mi][ni][r] - mnew);
      // packed P write: 4 consecutive tk per 8B store
      int qrow = mi * 16 + lo;
#pragma unroll
      for (int ni = 0; ni < 4; ni++) {
        u32x2 w;
        w[0] = cvtpk(sc[mi][ni][0], sc[mi][ni][1]);
        w[1] = cvtpk(sc[mi][ni][2], sc[mi][ni][3]);
        *(u32x2*)(pl + (qrow * 128 + ((ni * 32 + hi * 8) ^ ((qrow & 7) << 4)))) = w;
      }
    }
    // PV swapped: O^T[d][q] += V^T[d][tk] * P^T[tk][q]; row-sums via mfma(ones, P)
#pragma unroll
    for (int kt = 0; kt < 2; kt++) {
      s16x8 pa[2];
#pragma unroll
      for (int mi = 0; mi < 2; mi++) {
        int qrow = mi * 16 + lo;
        pa[mi] = *(const s16x8*)(pl + (qrow * 128 + ((kt * 64 + hi * 16) ^ ((qrow & 7) << 4))));
      }
#pragma unroll
      for (int dm = 0; dm < 4; dm++) {
        int dr = dm * 16 + lo;
        s16x8 av = *(const s16x8*)(Vl[cur] + dr * 128 + ((kt * 64 + hi * 16) ^ ((dr & 7) << 4)));
        oacc[0][dm] = __builtin_amdgcn_mfma_f32_16x16x32_bf16(av, pa[0], oacc[0][dm], 0, 0, 0);
        oacc[1][dm] = __builtin_amdgcn_mfma_f32_16x16x32_bf16(av, pa[1], oacc[1][dm], 0, 0, 0);
      }
      lacc[0] = __builtin_amdgcn_mfma_f32_16x16x32_bf16(ones, pa[0], lacc[0], 0, 0, 0);
      lacc[1] = __builtin_amdgcn_mfma_f32_16x16x32_bf16(ones, pa[1], lacc[1], 0, 0, 0);
    }
  }
  // epilogue: O^T -> rt[b*NT+q][head*64+d]; q = lo (lane-local), d = dm*16+hi*4+r
#pragma unroll
  for (int mi = 0; mi < 2; mi++) {
    float inv = 1.f / lacc[mi][0];
    int q = q0 + mi * 16 + lo;
#pragma unroll
    for (int dm = 0; dm < 4; dm++) {
      u32x2 w;
      w[0] = cvtpk(oacc[mi][dm][0] * inv, oacc[mi][dm][1] * inv);
      w[1] = cvtpk(oacc[mi][dm][2] * inv, oacc[mi][dm][3] * inv);
      *(u32x2*)(rt + (size_t)(b * NT + q) * NC + head * 64 + dm * 16 + hi * 4) = w;
    }
  }
}

// -------- kernel 5: out-proj GEMM + bias + residual (triple-buffer, 1 barrier/K-step) --------
__global__ __launch_bounds__(256) void k_proj(const unsigned short* __restrict__ wpb,
    const unsigned short* __restrict__ rt, const float* __restrict__ bproj,
    const float* __restrict__ x, float* __restrict__ out) {
  __shared__ char LB[49152];   // 3 × [A:8K|B:8K]
  int n0 = blockIdx.x * 128;
  int m0 = blockIdx.y * 128;
  int b = blockIdx.z;
  int tid = threadIdx.x, lane = tid & 63, wid = tid >> 6;
  int wr = wid >> 1, wc = wid & 1;
  int arow = lane >> 2, acol = (lane & 3) * 8;
  f32x4 acc[4][4] = {};
#pragma unroll
  for (int t0 = 0; t0 < 2; t0++) {
#pragma unroll
    for (int cc = 0; cc < 2; cc++) {
      int ci = wid * 2 + cc;
      const unsigned short* ga = wpb + (size_t)(m0 + ci * 16 + arow) * NC + t0 * 32 + acol;
      __builtin_amdgcn_global_load_lds((const AS1 unsigned int*)ga,
                                       (AS3 unsigned int*)(LB + t0 * 16384 + ci * 1024), 16, 0, 0);
      const unsigned short* gb = rt + (size_t)(b * NT + n0 + ci * 16 + arow) * NC + t0 * 32 + acol;
      __builtin_amdgcn_global_load_lds((const AS1 unsigned int*)gb,
                                       (AS3 unsigned int*)(LB + t0 * 16384 + 8192 + ci * 1024), 16, 0, 0);
    }
  }
  for (int ks = 0; ks < 16; ks++) {
    char* Ac = LB + (ks % 3) * 16384;
    char* Bc = Ac + 8192;
    if (ks < 14) {
      asm volatile("s_waitcnt vmcnt(4)" ::: "memory");
    } else {
      asm volatile("s_waitcnt vmcnt(0)" ::: "memory");
    }
    __builtin_amdgcn_s_barrier();
    __builtin_amdgcn_sched_barrier(0);
    if (ks + 2 < 16) {
      int k0n = (ks + 2) * 32;
      char* An = LB + ((ks + 2) % 3) * 16384;
#pragma unroll
      for (int cc = 0; cc < 2; cc++) {
        int ci = wid * 2 + cc;
        const unsigned short* ga = wpb + (size_t)(m0 + ci * 16 + arow) * NC + k0n + acol;
        __builtin_amdgcn_global_load_lds((const AS1 unsigned int*)ga,
                                         (AS3 unsigned int*)(An + ci * 1024), 16, 0, 0);
        const unsigned short* gb = rt + (size_t)(b * NT + n0 + ci * 16 + arow) * NC + k0n + acol;
        __builtin_amdgcn_global_load_lds((const AS1 unsigned int*)gb,
                                         (AS3 unsigned int*)(An + 8192 + ci * 1024), 16, 0, 0);
      }
    }
    s16x8 af[4], bfv[4];
#pragma unroll
    for (int mi = 0; mi < 4; mi++)
      af[mi] = *(const s16x8*)(Ac + ((wr * 64 + mi * 16 + (lane & 15)) * 32 + (lane >> 4) * 8) * 2);
#pragma unroll
    for (int ni = 0; ni < 4; ni++)
      bfv[ni] = *(const s16x8*)(Bc + ((wc * 64 + ni * 16 + (lane & 15)) * 32 + (lane >> 4) * 8) * 2);
#pragma unroll
    for (int mi = 0; mi < 4; mi++)
#pragma unroll
      for (int ni = 0; ni < 4; ni++)
        acc[mi][ni] = __builtin_amdgcn_mfma_f32_16x16x32_bf16(af[mi], bfv[ni], acc[mi][ni], 0, 0, 0);
  }
#pragma unroll
  for (int mi = 0; mi < 4; mi++) {
    int o_base = m0 + wr * 64 + mi * 16 + (lane >> 4) * 4;
#pragma unroll
    for (int r = 0; r < 4; r++) {
      int o = o_base + r;
      float bp = bproj[o];
#pragma unroll
      for (int ni = 0; ni < 4; ni++) {
        int t = n0 + wc * 64 + ni * 16 + (lane & 15);
        size_t idx = (size_t)(b * NC + o) * NT + t;
        out[idx] = acc[mi][ni][r] + bp + x[idx];
      }
    }
  }
}

extern "C" void kernel_launch(void* const* d_in, const int* in_sizes, int n_in,
                              void* d_out, int out_size, void* d_ws, size_t ws_size,
                              hipStream_t stream) {
  const float* x   = (const float*)d_in[0];
  const float* gsc = (const float*)d_in[1];
  const float* gbi = (const float*)d_in[2];
  const float* wq  = (const float*)d_in[3];
  const float* bq  = (const float*)d_in[4];
  const float* wp  = (const float*)d_in[5];
  const float* bp  = (const float*)d_in[6];
  float* out = (float*)d_out;
  char* ws = (char*)d_ws;

  float* affA = (float*)ws;                                   // 16*512 f32
  float* affB = affA + NB * NC;                               // 16*512 f32
  unsigned short* wqb = (unsigned short*)(ws + 65536);        // 1536*512 bf16
  unsigned short* wpb = wqb + (size_t)NOC * NC;               // 512*512 bf16
  unsigned short* xt  = (unsigned short*)(ws + 2162688);      // [16][1024][512] bf16
  unsigned short* qt  = xt + (size_t)NB * NT * NC;            // [128][1024][64] bf16 (scaled)
  unsigned short* ktb = qt + (size_t)128 * NT * 64;           // [128][1024][64] bf16 (scaled)
  unsigned short* vvb = ktb + (size_t)128 * NT * 64;          // [128][64][1024] bf16
  unsigned short* rt  = vvb + (size_t)128 * NT * 64;          // [16][1024][512] bf16

  k_convert<<<dim3(1024), 256, 0, stream>>>(wq, wp, wqb, wpb);
  k_gnstats<<<dim3(512), 256, 0, stream>>>(x, gsc, gbi, affA, affB);
  k_norm_t<<<dim3(2048), 256, 0, stream>>>(x, affA, affB, xt);
  k_qkv<<<dim3(8, 12, 16), 256, 0, stream>>>(wqb, xt, bq, qt, ktb, vvb);
  k_attn<<<dim3(4, 128), 512, 0, stream>>>(qt, ktb, vvb, rt);
  k_proj<<<dim3(8, 4, 16), 256, 0, stream>>>(wpb, rt, bp, x, out);
}

// Round 21
// 127.339 us; speedup vs baseline: 1.0112x; 1.0112x over previous
//
#include <hip/hip_runtime.h>
#include <stdint.h>
#include <stddef.h>

#define NB 16
#define NC 512
#define NT 1024
#define NHEAD 8
#define NOC 1536

typedef float f32x4 __attribute__((ext_vector_type(4)));
typedef short s16x8 __attribute__((ext_vector_type(8)));
typedef short s16x4 __attribute__((ext_vector_type(4)));
typedef unsigned int u32x2 __attribute__((ext_vector_type(2)));

#define AS1 __attribute__((address_space(1)))
#define AS3 __attribute__((address_space(3)))

static __device__ __forceinline__ unsigned short f2bf(float f) {
  union { float fv; unsigned int u; } v; v.fv = f;
  return (unsigned short)((v.u + 0x7fffu + ((v.u >> 16) & 1u)) >> 16);
}

// v_cvt_pk_bf16_f32: dst.lo16 = bf16(lo), dst.hi16 = bf16(hi)
static __device__ __forceinline__ unsigned int cvtpk(float lo, float hi) {
  unsigned int r;
  asm("v_cvt_pk_bf16_f32 %0, %1, %2" : "=v"(r) : "v"(lo), "v"(hi));
  return r;
}

// v_exp_f32: D = 2^S0 (gfx950 ISA §3) — exp2-domain softmax
static __device__ __forceinline__ float exp2_hw(float x) {
  float r;
  asm("v_exp_f32 %0, %1" : "=v"(r) : "v"(x));
  return r;
}

// ---------------- kernel 0: weights fp32 -> bf16 ----------------
__global__ void k_convert(const float* __restrict__ wq, const float* __restrict__ wp,
                          unsigned short* __restrict__ wqb, unsigned short* __restrict__ wpb) {
  int i = blockIdx.x * 256 + threadIdx.x;
  int step = gridDim.x * 256;
  for (int idx = i; idx < NOC * NC; idx += step) wqb[idx] = f2bf(wq[idx]);
  for (int idx = i; idx < NC * NC; idx += step) wpb[idx] = f2bf(wp[idx]);
}

// ---------------- kernel 1: groupnorm stats -> per (b,c) affine ----------------
__global__ __launch_bounds__(256) void k_gnstats(const float* __restrict__ x,
    const float* __restrict__ gsc, const float* __restrict__ gbi,
    float* __restrict__ affA, float* __restrict__ affB) {
  int b = blockIdx.x >> 5, g = blockIdx.x & 31;
  const f32x4* p4 = (const f32x4*)(x + (size_t)(b * NC + g * 16) * NT);
  float s = 0.f, ss = 0.f;
  for (int i = threadIdx.x; i < 4096; i += 256) {
    f32x4 v = p4[i];
    s += v[0] + v[1] + v[2] + v[3];
    ss += v[0] * v[0] + v[1] * v[1] + v[2] * v[2] + v[3] * v[3];
  }
#pragma unroll
  for (int off = 32; off > 0; off >>= 1) { s += __shfl_down(s, off); ss += __shfl_down(ss, off); }
  __shared__ float red[4][2];
  if ((threadIdx.x & 63) == 0) { red[threadIdx.x >> 6][0] = s; red[threadIdx.x >> 6][1] = ss; }
  __syncthreads();
  if (threadIdx.x < 16) {
    float st = red[0][0] + red[1][0] + red[2][0] + red[3][0];
    float sst = red[0][1] + red[1][1] + red[2][1] + red[3][1];
    float mean = st * (1.f / 16384.f);
    float var = sst * (1.f / 16384.f) - mean * mean;
    float rstd = rsqrtf(var + 1e-5f);
    int c = g * 16 + threadIdx.x;
    float a = rstd * gsc[c];
    affA[b * NC + c] = a;
    affB[b * NC + c] = gbi[c] - mean * a;
  }
}

// ---------------- kernel 2: normalize + transpose -> xt[b][t][c] bf16 ----------------
__global__ __launch_bounds__(256) void k_norm_t(const float* __restrict__ x,
    const float* __restrict__ affA, const float* __restrict__ affB,
    unsigned short* __restrict__ xt) {
  __shared__ float sm[64][65];
  int bx = blockIdx.x;
  int tt = bx & 15, ct = (bx >> 4) & 7, b = bx >> 7;
  int c0 = ct * 64, t0 = tt * 64;
  int tid = threadIdx.x;
#pragma unroll
  for (int it = 0; it < 4; it++) {
    int row = (tid >> 4) + it * 16;
    int col = (tid & 15) * 4;
    int c = c0 + row;
    f32x4 v = *(const f32x4*)(x + (size_t)(b * NC + c) * NT + t0 + col);
    float a = affA[b * NC + c], bb = affB[b * NC + c];
    sm[row][col + 0] = v[0] * a + bb;
    sm[row][col + 1] = v[1] * a + bb;
    sm[row][col + 2] = v[2] * a + bb;
    sm[row][col + 3] = v[3] * a + bb;
  }
  __syncthreads();
#pragma unroll
  for (int it = 0; it < 2; it++) {
    int t = (tid >> 3) + it * 32;
    int cb = (tid & 7) * 8;
    s16x8 o;
#pragma unroll
    for (int j = 0; j < 8; j++) o[j] = (short)f2bf(sm[cb + j][t]);
    *(s16x8*)(xt + (size_t)(b * NT + t0 + t) * NC + c0 + cb) = o;
  }
}

// -------- kernel 3: QKV GEMM (triple-buffer, 1 barrier/K-step; Tr aliased post-loop) --------
__global__ __launch_bounds__(256) void k_qkv(const unsigned short* __restrict__ wqb,
    const unsigned short* __restrict__ xt, const float* __restrict__ bqkv,
    unsigned short* __restrict__ qt, unsigned short* __restrict__ ktb,
    unsigned short* __restrict__ vvb) {
  __shared__ char LB[49152];   // 3 × [A:8K|B:8K]; epilogue reuses first 32K as per-wave Tr
  int n0 = blockIdx.x * 128;
  int m0 = blockIdx.y * 128;
  int b = blockIdx.z;
  int tid = threadIdx.x, lane = tid & 63, wid = tid >> 6;
  int wr = wid >> 1, wc = wid & 1;
  int arow = lane >> 2, acol = (lane & 3) * 8;
  f32x4 acc[4][4] = {};
  // prologue: stage ks=0 -> buf0, ks=1 -> buf1
#pragma unroll
  for (int t0 = 0; t0 < 2; t0++) {
#pragma unroll
    for (int cc = 0; cc < 2; cc++) {
      int ci = wid * 2 + cc;
      const unsigned short* ga = wqb + (size_t)(m0 + ci * 16 + arow) * NC + t0 * 32 + acol;
      __builtin_amdgcn_global_load_lds((const AS1 unsigned int*)ga,
                                       (AS3 unsigned int*)(LB + t0 * 16384 + ci * 1024), 16, 0, 0);
      const unsigned short* gb = xt + (size_t)(b * NT + n0 + ci * 16 + arow) * NC + t0 * 32 + acol;
      __builtin_amdgcn_global_load_lds((const AS1 unsigned int*)gb,
                                       (AS3 unsigned int*)(LB + t0 * 16384 + 8192 + ci * 1024), 16, 0, 0);
    }
  }
  for (int ks = 0; ks < 16; ks++) {
    char* Ac = LB + (ks % 3) * 16384;
    char* Bc = Ac + 8192;
    if (ks < 14) {
      asm volatile("s_waitcnt vmcnt(4)" ::: "memory");   // tile ks landed (ks+1 in flight)
    } else {
      asm volatile("s_waitcnt vmcnt(0)" ::: "memory");
    }
    __builtin_amdgcn_s_barrier();
    __builtin_amdgcn_sched_barrier(0);
    if (ks + 2 < 16) {
      // prefetch tile ks+2 into buf[(ks+2)%3] — its last readers passed the barrier above
      int k0n = (ks + 2) * 32;
      char* An = LB + ((ks + 2) % 3) * 16384;
#pragma unroll
      for (int cc = 0; cc < 2; cc++) {
        int ci = wid * 2 + cc;
        const unsigned short* ga = wqb + (size_t)(m0 + ci * 16 + arow) * NC + k0n + acol;
        __builtin_amdgcn_global_load_lds((const AS1 unsigned int*)ga,
                                         (AS3 unsigned int*)(An + ci * 1024), 16, 0, 0);
        const unsigned short* gb = xt + (size_t)(b * NT + n0 + ci * 16 + arow) * NC + k0n + acol;
        __builtin_amdgcn_global_load_lds((const AS1 unsigned int*)gb,
                                         (AS3 unsigned int*)(An + 8192 + ci * 1024), 16, 0, 0);
      }
    }
    s16x8 af[4], bfv[4];
#pragma unroll
    for (int mi = 0; mi < 4; mi++)
      af[mi] = *(const s16x8*)(Ac + ((wr * 64 + mi * 16 + (lane & 15)) * 32 + (lane >> 4) * 8) * 2);
#pragma unroll
    for (int ni = 0; ni < 4; ni++)
      bfv[ni] = *(const s16x8*)(Bc + ((wc * 64 + ni * 16 + (lane & 15)) * 32 + (lane >> 4) * 8) * 2);
#pragma unroll
    for (int mi = 0; mi < 4; mi++)
#pragma unroll
      for (int ni = 0; ni < 4; ni++)
        acc[mi][ni] = __builtin_amdgcn_mfma_f32_16x16x32_bf16(af[mi], bfv[ni], acc[mi][ni], 0, 0, 0);
  }
  __syncthreads();   // all waves done with LDS buffers before Tr aliasing
  // epilogue: per-wave private Tr region aliased onto the dead buffers
  char* tr = LB + wid * 8192;
  int o064 = m0 + wr * 64;
  int blk = (o064 >> 6) % 3;  // 0=q 1=k 2=v
  int head = o064 / 192;
  int bh = b * NHEAD + head;
  int n0w = n0 + wc * 64;
  // 64^-0.25 * sqrt(log2(e)) folded into q and k (softmax runs in exp2 domain)
  const float scale = 0.42466090014400953f;
  if (blk < 2) {
    // token-major [t][ch] via swizzled LDS transpose
#pragma unroll
    for (int mi = 0; mi < 4; mi++) {
      int o_loc = mi * 16 + (lane >> 4) * 4;
      float b0 = bqkv[o064 + o_loc + 0], b1 = bqkv[o064 + o_loc + 1];
      float b2 = bqkv[o064 + o_loc + 2], b3 = bqkv[o064 + o_loc + 3];
#pragma unroll
      for (int ni = 0; ni < 4; ni++) {
        int t_loc = ni * 16 + (lane & 15);
        s16x4 pk;
        pk[0] = (short)f2bf((acc[mi][ni][0] + b0) * scale);
        pk[1] = (short)f2bf((acc[mi][ni][1] + b1) * scale);
        pk[2] = (short)f2bf((acc[mi][ni][2] + b2) * scale);
        pk[3] = (short)f2bf((acc[mi][ni][3] + b3) * scale);
        *(s16x4*)(tr + t_loc * 128 + ((o_loc * 2) ^ ((t_loc & 7) << 4))) = pk;
      }
    }
    unsigned short* outp = (blk == 0) ? qt : ktb;
#pragma unroll
    for (int pass = 0; pass < 8; pass++) {
      int t = pass * 8 + (lane >> 3);
      int cb = (lane & 7) * 16;
      s16x8 v = *(const s16x8*)(tr + t * 128 + (cb ^ ((t & 7) << 4)));
      *(s16x8*)(outp + (size_t)(bh * NT + n0w + t) * 64 + (cb >> 1)) = v;
    }
  } else {
    // v channel-major [ch][t], C-tile is already row-major in o
#pragma unroll
    for (int mi = 0; mi < 4; mi++) {
#pragma unroll
      for (int ni = 0; ni < 4; ni++) {
        int t_loc = ni * 16 + (lane & 15);
#pragma unroll
        for (int r = 0; r < 4; r++) {
          int o_loc = mi * 16 + (lane >> 4) * 4 + r;
          *(unsigned short*)(tr + o_loc * 128 + t_loc * 2) =
              f2bf(acc[mi][ni][r] + bqkv[o064 + o_loc]);
        }
      }
    }
#pragma unroll
    for (int pass = 0; pass < 8; pass++) {
      int o = pass * 8 + (lane >> 3);
      int tb = (lane & 7) * 16;
      s16x8 v = *(const s16x8*)(tr + o * 128 + tb);
      *(s16x8*)(vvb + (size_t)(bh * 64 + o) * NT + n0w + (tb >> 1)) = v;
    }
  }
}

// ---- kernel 4: flash attention (dbuf K/V + counted vmcnt + raw barriers; MFMA row-sums) ----
__global__ __launch_bounds__(512, 4) void k_attn(const unsigned short* __restrict__ qt,
    const unsigned short* __restrict__ ktb, const unsigned short* __restrict__ vvb,
    unsigned short* __restrict__ rt) {
  __shared__ char Kl[2][8192];        // [64 tk][64 ch] bf16, row-swizzled image, double-buffered
  __shared__ char Vl[2][8192];        // [64 ch][64 tk] bf16, row-swizzled image, double-buffered
  __shared__ char Pl[8][4096];        // per-wave [32 q][64 tk] bf16, row-swizzled
  int qt0 = blockIdx.x * 256;
  int bh = blockIdx.y;
  int b = bh >> 3, head = bh & 7;
  int tid = threadIdx.x, lane = tid & 63, wid = tid >> 6;
  int hi = lane >> 4, lo = lane & 15;
  int q0 = qt0 + wid * 32;
  // Q as B-fragments: aq[mi][ko] = Q[q0+mi*16+lo][ko*32 + hi*8 .. +8]
  s16x8 aq[2][2];
#pragma unroll
  for (int mi = 0; mi < 2; mi++)
#pragma unroll
    for (int ko = 0; ko < 2; ko++)
      aq[mi][ko] = *(const s16x8*)(qt + (size_t)(bh * NT + q0 + mi * 16 + lo) * 64 +
                                   ko * 32 + hi * 8);
  f32x4 oacc[2][4] = {};              // O^T: col q = lo, row d = hi*4+r (per mi, dm)
  f32x4 lacc[2] = {};                 // row-sum accumulator via mfma(ones, P): all rows = l[q]
  float mrun[2] = {-1e30f, -1e30f};
  s16x8 ones;
#pragma unroll
  for (int j = 0; j < 8; j++) ones[j] = (short)0x3F80;   // bf16 1.0
  char* pl = (char*)Pl[wid];
  // async-staging coords: wave wid covers rows wid*8..wid*8+7 (1 KB) of each 8 KB tile;
  // LDS dest linear, swizzle folded into the per-lane GLOBAL address (involution).
  int srow = (wid << 3) + (lane >> 3);
  int soff = ((lane & 7) << 4) ^ ((srow & 7) << 4);
  const char* kb = (const char*)ktb + ((size_t)bh * NT + srow) * 128 + soff;
  const char* vb = (const char*)vvb + ((size_t)(bh * 64 + srow)) * 2048 + soff;
  // prologue: issue tile 0 into buf 0
  __builtin_amdgcn_global_load_lds((const AS1 unsigned int*)kb,
                                   (AS3 unsigned int*)(Kl[0] + (wid << 10)), 16, 0, 0);
  __builtin_amdgcn_global_load_lds((const AS1 unsigned int*)vb,
                                   (AS3 unsigned int*)(Vl[0] + (wid << 10)), 16, 0, 0);
  for (int kv = 0; kv < 16; kv++) {
    int cur = kv & 1;
    if (kv < 15) {
      // prefetch tile kv+1 into the other buffer (its last readers passed the tail barrier)
      __builtin_amdgcn_global_load_lds((const AS1 unsigned int*)(kb + (size_t)(kv + 1) * 8192),
                                       (AS3 unsigned int*)(Kl[cur ^ 1] + (wid << 10)), 16, 0, 0);
      __builtin_amdgcn_global_load_lds((const AS1 unsigned int*)(vb + (size_t)(kv + 1) * 128),
                                       (AS3 unsigned int*)(Vl[cur ^ 1] + (wid << 10)), 16, 0, 0);
      asm volatile("s_waitcnt vmcnt(2)" ::: "memory");   // current tile's 2 loads done
    } else {
      asm volatile("s_waitcnt vmcnt(0)" ::: "memory");
    }
    __builtin_amdgcn_s_barrier();
    __builtin_amdgcn_sched_barrier(0);
    // S^T = K * Q^T : sc[mi][ni] holds S[tk=ni*16+hi*4+r][q=mi*16+lo], exp2 domain
    f32x4 sc[2][4] = {};
#pragma unroll
    for (int ni = 0; ni < 4; ni++) {
      int tkr = ni * 16 + lo;
#pragma unroll
      for (int ko = 0; ko < 2; ko++) {
        s16x8 kf = *(const s16x8*)(Kl[cur] + tkr * 128 + ((ko * 64 + hi * 16) ^ ((tkr & 7) << 4)));
        sc[0][ni] = __builtin_amdgcn_mfma_f32_16x16x32_bf16(kf, aq[0][ko], sc[0][ni], 0, 0, 0);
        sc[1][ni] = __builtin_amdgcn_mfma_f32_16x16x32_bf16(kf, aq[1][ko], sc[1][ni], 0, 0, 0);
      }
    }
    // online softmax (exp2 domain), defer-max (THR=8): per q = lo, + 2 shfl over hi
#pragma unroll
    for (int mi = 0; mi < 2; mi++) {
      float a0 = fmaxf(fmaxf(sc[mi][0][0], sc[mi][0][1]), fmaxf(sc[mi][0][2], sc[mi][0][3]));
      float a1 = fmaxf(fmaxf(sc[mi][1][0], sc[mi][1][1]), fmaxf(sc[mi][1][2], sc[mi][1][3]));
      float a2 = fmaxf(fmaxf(sc[mi][2][0], sc[mi][2][1]), fmaxf(sc[mi][2][2], sc[mi][2][3]));
      float a3 = fmaxf(fmaxf(sc[mi][3][0], sc[mi][3][1]), fmaxf(sc[mi][3][2], sc[mi][3][3]));
      float tm = fmaxf(fmaxf(a0, a1), fmaxf(a2, a3));
      tm = fmaxf(tm, __shfl_xor(tm, 16));
      tm = fmaxf(tm, __shfl_xor(tm, 32));
      int resc = __any(tm > mrun[mi] + 8.f);   // wave-uniform
      float mnew = mrun[mi];
      if (resc) {
        mnew = fmaxf(mrun[mi], tm);
        float fac = exp2_hw(mrun[mi] - mnew);
        mrun[mi] = mnew;
#pragma unroll
        for (int dm = 0; dm < 4; dm++)
#pragma unroll
          for (int r = 0; r < 4; r++) oacc[mi][dm][r] *= fac;
#pragma unroll
        for (int r = 0; r < 4; r++) lacc[mi][r] *= fac;
      }
#pragma unroll
      for (int ni = 0; ni < 4; ni++)
#pragma unroll
        for (int r = 0; r < 4; r++) sc[mi][ni][r] = exp2_hw(sc[mi][ni][r] - mnew);
      // packed P write: 4 consecutive tk per 8B store
      int qrow = mi * 16 + lo;
#pragma unroll
      for (int ni = 0; ni < 4; ni++) {
        u32x2 w;
        w[0] = cvtpk(sc[mi][ni][0], sc[mi][ni][1]);
        w[1] = cvtpk(sc[mi][ni][2], sc[mi][ni][3]);
        *(u32x2*)(pl + (qrow * 128 + ((ni * 32 + hi * 8) ^ ((qrow & 7) << 4)))) = w;
      }
    }
    // PV swapped: O^T[d][q] += V^T[d][tk] * P^T[tk][q]; row-sums via mfma(ones, P)
#pragma unroll
    for (int kt = 0; kt < 2; kt++) {
      s16x8 pa[2];
#pragma unroll
      for (int mi = 0; mi < 2; mi++) {
        int qrow = mi * 16 + lo;
        pa[mi] = *(const s16x8*)(pl + (qrow * 128 + ((kt * 64 + hi * 16) ^ ((qrow & 7) << 4))));
      }
#pragma unroll
      for (int dm = 0; dm < 4; dm++) {
        int dr = dm * 16 + lo;
        s16x8 av = *(const s16x8*)(Vl[cur] + dr * 128 + ((kt * 64 + hi * 16) ^ ((dr & 7) << 4)));
        oacc[0][dm] = __builtin_amdgcn_mfma_f32_16x16x32_bf16(av, pa[0], oacc[0][dm], 0, 0, 0);
        oacc[1][dm] = __builtin_amdgcn_mfma_f32_16x16x32_bf16(av, pa[1], oacc[1][dm], 0, 0, 0);
      }
      lacc[0] = __builtin_amdgcn_mfma_f32_16x16x32_bf16(ones, pa[0], lacc[0], 0, 0, 0);
      lacc[1] = __builtin_amdgcn_mfma_f32_16x16x32_bf16(ones, pa[1], lacc[1], 0, 0, 0);
    }
    // tail barrier: all waves done reading buf[cur^1]-to-be-overwritten & P before next iter
    __builtin_amdgcn_s_barrier();
  }
  // epilogue: O^T -> rt[b*NT+q][head*64+d]; q = lo (lane-local), d = dm*16+hi*4+r
#pragma unroll
  for (int mi = 0; mi < 2; mi++) {
    float inv = 1.f / lacc[mi][0];
    int q = q0 + mi * 16 + lo;
#pragma unroll
    for (int dm = 0; dm < 4; dm++) {
      u32x2 w;
      w[0] = cvtpk(oacc[mi][dm][0] * inv, oacc[mi][dm][1] * inv);
      w[1] = cvtpk(oacc[mi][dm][2] * inv, oacc[mi][dm][3] * inv);
      *(u32x2*)(rt + (size_t)(b * NT + q) * NC + head * 64 + dm * 16 + hi * 4) = w;
    }
  }
}

// -------- kernel 5: out-proj GEMM + bias + residual (triple-buffer, 1 barrier/K-step) --------
__global__ __launch_bounds__(256) void k_proj(const unsigned short* __restrict__ wpb,
    const unsigned short* __restrict__ rt, const float* __restrict__ bproj,
    const float* __restrict__ x, float* __restrict__ out) {
  __shared__ char LB[49152];   // 3 × [A:8K|B:8K]
  int n0 = blockIdx.x * 128;
  int m0 = blockIdx.y * 128;
  int b = blockIdx.z;
  int tid = threadIdx.x, lane = tid & 63, wid = tid >> 6;
  int wr = wid >> 1, wc = wid & 1;
  int arow = lane >> 2, acol = (lane & 3) * 8;
  f32x4 acc[4][4] = {};
#pragma unroll
  for (int t0 = 0; t0 < 2; t0++) {
#pragma unroll
    for (int cc = 0; cc < 2; cc++) {
      int ci = wid * 2 + cc;
      const unsigned short* ga = wpb + (size_t)(m0 + ci * 16 + arow) * NC + t0 * 32 + acol;
      __builtin_amdgcn_global_load_lds((const AS1 unsigned int*)ga,
                                       (AS3 unsigned int*)(LB + t0 * 16384 + ci * 1024), 16, 0, 0);
      const unsigned short* gb = rt + (size_t)(b * NT + n0 + ci * 16 + arow) * NC + t0 * 32 + acol;
      __builtin_amdgcn_global_load_lds((const AS1 unsigned int*)gb,
                                       (AS3 unsigned int*)(LB + t0 * 16384 + 8192 + ci * 1024), 16, 0, 0);
    }
  }
  for (int ks = 0; ks < 16; ks++) {
    char* Ac = LB + (ks % 3) * 16384;
    char* Bc = Ac + 8192;
    if (ks < 14) {
      asm volatile("s_waitcnt vmcnt(4)" ::: "memory");
    } else {
      asm volatile("s_waitcnt vmcnt(0)" ::: "memory");
    }
    __builtin_amdgcn_s_barrier();
    __builtin_amdgcn_sched_barrier(0);
    if (ks + 2 < 16) {
      int k0n = (ks + 2) * 32;
      char* An = LB + ((ks + 2) % 3) * 16384;
#pragma unroll
      for (int cc = 0; cc < 2; cc++) {
        int ci = wid * 2 + cc;
        const unsigned short* ga = wpb + (size_t)(m0 + ci * 16 + arow) * NC + k0n + acol;
        __builtin_amdgcn_global_load_lds((const AS1 unsigned int*)ga,
                                         (AS3 unsigned int*)(An + ci * 1024), 16, 0, 0);
        const unsigned short* gb = rt + (size_t)(b * NT + n0 + ci * 16 + arow) * NC + k0n + acol;
        __builtin_amdgcn_global_load_lds((const AS1 unsigned int*)gb,
                                         (AS3 unsigned int*)(An + 8192 + ci * 1024), 16, 0, 0);
      }
    }
    s16x8 af[4], bfv[4];
#pragma unroll
    for (int mi = 0; mi < 4; mi++)
      af[mi] = *(const s16x8*)(Ac + ((wr * 64 + mi * 16 + (lane & 15)) * 32 + (lane >> 4) * 8) * 2);
#pragma unroll
    for (int ni = 0; ni < 4; ni++)
      bfv[ni] = *(const s16x8*)(Bc + ((wc * 64 + ni * 16 + (lane & 15)) * 32 + (lane >> 4) * 8) * 2);
#pragma unroll
    for (int mi = 0; mi < 4; mi++)
#pragma unroll
      for (int ni = 0; ni < 4; ni++)
        acc[mi][ni] = __builtin_amdgcn_mfma_f32_16x16x32_bf16(af[mi], bfv[ni], acc[mi][ni], 0, 0, 0);
  }
#pragma unroll
  for (int mi = 0; mi < 4; mi++) {
    int o_base = m0 + wr * 64 + mi * 16 + (lane >> 4) * 4;
#pragma unroll
    for (int r = 0; r < 4; r++) {
      int o = o_base + r;
      float bp = bproj[o];
#pragma unroll
      for (int ni = 0; ni < 4; ni++) {
        int t = n0 + wc * 64 + ni * 16 + (lane & 15);
        size_t idx = (size_t)(b * NC + o) * NT + t;
        out[idx] = acc[mi][ni][r] + bp + x[idx];
      }
    }
  }
}

extern "C" void kernel_launch(void* const* d_in, const int* in_sizes, int n_in,
                              void* d_out, int out_size, void* d_ws, size_t ws_size,
                              hipStream_t stream) {
  const float* x   = (const float*)d_in[0];
  const float* gsc = (const float*)d_in[1];
  const float* gbi = (const float*)d_in[2];
  const float* wq  = (const float*)d_in[3];
  const float* bq  = (const float*)d_in[4];
  const float* wp  = (const float*)d_in[5];
  const float* bp  = (const float*)d_in[6];
  float* out = (float*)d_out;
  char* ws = (char*)d_ws;

  float* affA = (float*)ws;                                   // 16*512 f32
  float* affB = affA + NB * NC;                               // 16*512 f32
  unsigned short* wqb = (unsigned short*)(ws + 65536);        // 1536*512 bf16
  unsigned short* wpb = wqb + (size_t)NOC * NC;               // 512*512 bf16
  unsigned short* xt  = (unsigned short*)(ws + 2162688);      // [16][1024][512] bf16
  unsigned short* qt  = xt + (size_t)NB * NT * NC;            // [128][1024][64] bf16 (scaled)
  unsigned short* ktb = qt + (size_t)128 * NT * 64;           // [128][1024][64] bf16 (scaled)
  unsigned short* vvb = ktb + (size_t)128 * NT * 64;          // [128][64][1024] bf16
  unsigned short* rt  = vvb + (size_t)128 * NT * 64;          // [16][1024][512] bf16

  k_convert<<<dim3(1024), 256, 0, stream>>>(wq, wp, wqb, wpb);
  k_gnstats<<<dim3(512), 256, 0, stream>>>(x, gsc, gbi, affA, affB);
  k_norm_t<<<dim3(2048), 256, 0, stream>>>(x, affA, affB, xt);
  k_qkv<<<dim3(8, 12, 16), 256, 0, stream>>>(wqb, xt, bq, qt, ktb, vvb);
  k_attn<<<dim3(4, 128), 512, 0, stream>>>(qt, ktb, vvb, rt);
  k_proj<<<dim3(8, 4, 16), 256, 0, stream>>>(wpb, rt, bp, x, out);
}

// Round 22
// 124.380 us; speedup vs baseline: 1.0353x; 1.0238x over previous
//
#include <hip/hip_runtime.h>
#include <stdint.h>
#include <stddef.h>

#define NB 16
#define NC 512
#define NT 1024
#define NHEAD 8
#define NOC 1536

typedef float f32x4 __attribute__((ext_vector_type(4)));
typedef short s16x8 __attribute__((ext_vector_type(8)));
typedef short s16x4 __attribute__((ext_vector_type(4)));
typedef unsigned int u32x2 __attribute__((ext_vector_type(2)));

#define AS1 __attribute__((address_space(1)))
#define AS3 __attribute__((address_space(3)))

static __device__ __forceinline__ unsigned short f2bf(float f) {
  union { float fv; unsigned int u; } v; v.fv = f;
  return (unsigned short)((v.u + 0x7fffu + ((v.u >> 16) & 1u)) >> 16);
}

// v_cvt_pk_bf16_f32: dst.lo16 = bf16(lo), dst.hi16 = bf16(hi)
static __device__ __forceinline__ unsigned int cvtpk(float lo, float hi) {
  unsigned int r;
  asm("v_cvt_pk_bf16_f32 %0, %1, %2" : "=v"(r) : "v"(lo), "v"(hi));
  return r;
}

// v_exp_f32: D = 2^S0 (gfx950 ISA §3) — exp2-domain softmax
static __device__ __forceinline__ float exp2_hw(float x) {
  float r;
  asm("v_exp_f32 %0, %1" : "=v"(r) : "v"(x));
  return r;
}

// ---------------- kernel 0: weights fp32 -> bf16 ----------------
__global__ void k_convert(const float* __restrict__ wq, const float* __restrict__ wp,
                          unsigned short* __restrict__ wqb, unsigned short* __restrict__ wpb) {
  int i = blockIdx.x * 256 + threadIdx.x;
  int step = gridDim.x * 256;
  for (int idx = i; idx < NOC * NC; idx += step) wqb[idx] = f2bf(wq[idx]);
  for (int idx = i; idx < NC * NC; idx += step) wpb[idx] = f2bf(wp[idx]);
}

// ---- kernel 1: FUSED groupnorm (stats + normalize + transpose), single read of x ----
// one block per (b, g): 16 channels x 1024 tokens = 64 KB fp32 slab in LDS
__global__ __launch_bounds__(256) void k_gn(const float* __restrict__ x,
    const float* __restrict__ gsc, const float* __restrict__ gbi,
    unsigned short* __restrict__ xt) {
  __shared__ float xs[16 * 1024];     // [c][t] fp32, 64 KB
  __shared__ float red[4][2];
  __shared__ float mv[2];
  int b = blockIdx.x >> 5, g = blockIdx.x & 31;
  int tid = threadIdx.x;
  const f32x4* p4 = (const f32x4*)(x + (size_t)(b * NC + g * 16) * NT);
  f32x4* s4 = (f32x4*)xs;
  float s = 0.f, ss = 0.f;
  for (int i = tid; i < 4096; i += 256) {
    f32x4 v = p4[i];
    s4[i] = v;
    s += v[0] + v[1] + v[2] + v[3];
    ss += v[0] * v[0] + v[1] * v[1] + v[2] * v[2] + v[3] * v[3];
  }
#pragma unroll
  for (int off = 32; off > 0; off >>= 1) { s += __shfl_down(s, off); ss += __shfl_down(ss, off); }
  if ((tid & 63) == 0) { red[tid >> 6][0] = s; red[tid >> 6][1] = ss; }
  __syncthreads();
  if (tid == 0) {
    float st = red[0][0] + red[1][0] + red[2][0] + red[3][0];
    float sst = red[0][1] + red[1][1] + red[2][1] + red[3][1];
    float mean = st * (1.f / 16384.f);
    float var = sst * (1.f / 16384.f) - mean * mean;
    mv[0] = mean;
    mv[1] = rsqrtf(var + 1e-5f);
  }
  __syncthreads();
  float mean = mv[0], rstd = mv[1];
  int c0 = (tid & 1) * 8;             // thread covers 8 channels; pairs cover one token row
  int cbase = g * 16 + c0;
  float a[8], bb[8];
#pragma unroll
  for (int j = 0; j < 8; j++) {
    a[j] = rstd * gsc[cbase + j];
    bb[j] = gbi[cbase + j] - mean * a[j];
  }
#pragma unroll
  for (int pass = 0; pass < 8; pass++) {
    int t = pass * 128 + (tid >> 1);
    s16x8 o;
#pragma unroll
    for (int j = 0; j < 8; j++)
      o[j] = (short)f2bf(xs[(c0 + j) * 1024 + t] * a[j] + bb[j]);
    *(s16x8*)(xt + (size_t)(b * NT + t) * NC + cbase) = o;
  }
}

// -------- kernel 3: QKV GEMM (triple-buffer, 1 barrier/K-step; Tr aliased post-loop) --------
__global__ __launch_bounds__(256) void k_qkv(const unsigned short* __restrict__ wqb,
    const unsigned short* __restrict__ xt, const float* __restrict__ bqkv,
    unsigned short* __restrict__ qt, unsigned short* __restrict__ ktb,
    unsigned short* __restrict__ vvb) {
  __shared__ char LB[49152];   // 3 × [A:8K|B:8K]; epilogue reuses first 32K as per-wave Tr
  int n0 = blockIdx.x * 128;
  int m0 = blockIdx.y * 128;
  int b = blockIdx.z;
  int tid = threadIdx.x, lane = tid & 63, wid = tid >> 6;
  int wr = wid >> 1, wc = wid & 1;
  int arow = lane >> 2, acol = (lane & 3) * 8;
  f32x4 acc[4][4] = {};
  // prologue: stage ks=0 -> buf0, ks=1 -> buf1
#pragma unroll
  for (int t0 = 0; t0 < 2; t0++) {
#pragma unroll
    for (int cc = 0; cc < 2; cc++) {
      int ci = wid * 2 + cc;
      const unsigned short* ga = wqb + (size_t)(m0 + ci * 16 + arow) * NC + t0 * 32 + acol;
      __builtin_amdgcn_global_load_lds((const AS1 unsigned int*)ga,
                                       (AS3 unsigned int*)(LB + t0 * 16384 + ci * 1024), 16, 0, 0);
      const unsigned short* gb = xt + (size_t)(b * NT + n0 + ci * 16 + arow) * NC + t0 * 32 + acol;
      __builtin_amdgcn_global_load_lds((const AS1 unsigned int*)gb,
                                       (AS3 unsigned int*)(LB + t0 * 16384 + 8192 + ci * 1024), 16, 0, 0);
    }
  }
  for (int ks = 0; ks < 16; ks++) {
    char* Ac = LB + (ks % 3) * 16384;
    char* Bc = Ac + 8192;
    if (ks < 14) {
      asm volatile("s_waitcnt vmcnt(4)" ::: "memory");   // tile ks landed (ks+1 in flight)
    } else {
      asm volatile("s_waitcnt vmcnt(0)" ::: "memory");
    }
    __builtin_amdgcn_s_barrier();
    __builtin_amdgcn_sched_barrier(0);
    if (ks + 2 < 16) {
      // prefetch tile ks+2 into buf[(ks+2)%3] — its last readers passed the barrier above
      int k0n = (ks + 2) * 32;
      char* An = LB + ((ks + 2) % 3) * 16384;
#pragma unroll
      for (int cc = 0; cc < 2; cc++) {
        int ci = wid * 2 + cc;
        const unsigned short* ga = wqb + (size_t)(m0 + ci * 16 + arow) * NC + k0n + acol;
        __builtin_amdgcn_global_load_lds((const AS1 unsigned int*)ga,
                                         (AS3 unsigned int*)(An + ci * 1024), 16, 0, 0);
        const unsigned short* gb = xt + (size_t)(b * NT + n0 + ci * 16 + arow) * NC + k0n + acol;
        __builtin_amdgcn_global_load_lds((const AS1 unsigned int*)gb,
                                         (AS3 unsigned int*)(An + 8192 + ci * 1024), 16, 0, 0);
      }
    }
    s16x8 af[4], bfv[4];
#pragma unroll
    for (int mi = 0; mi < 4; mi++)
      af[mi] = *(const s16x8*)(Ac + ((wr * 64 + mi * 16 + (lane & 15)) * 32 + (lane >> 4) * 8) * 2);
#pragma unroll
    for (int ni = 0; ni < 4; ni++)
      bfv[ni] = *(const s16x8*)(Bc + ((wc * 64 + ni * 16 + (lane & 15)) * 32 + (lane >> 4) * 8) * 2);
#pragma unroll
    for (int mi = 0; mi < 4; mi++)
#pragma unroll
      for (int ni = 0; ni < 4; ni++)
        acc[mi][ni] = __builtin_amdgcn_mfma_f32_16x16x32_bf16(af[mi], bfv[ni], acc[mi][ni], 0, 0, 0);
  }
  __syncthreads();   // all waves done with LDS buffers before Tr aliasing
  // epilogue: per-wave private Tr region aliased onto the dead buffers
  char* tr = LB + wid * 8192;
  int o064 = m0 + wr * 64;
  int blk = (o064 >> 6) % 3;  // 0=q 1=k 2=v
  int head = o064 / 192;
  int bh = b * NHEAD + head;
  int n0w = n0 + wc * 64;
  // 64^-0.25 * sqrt(log2(e)) folded into q and k (softmax runs in exp2 domain)
  const float scale = 0.42466090014400953f;
  if (blk < 2) {
    // token-major [t][ch] via swizzled LDS transpose
#pragma unroll
    for (int mi = 0; mi < 4; mi++) {
      int o_loc = mi * 16 + (lane >> 4) * 4;
      float b0 = bqkv[o064 + o_loc + 0], b1 = bqkv[o064 + o_loc + 1];
      float b2 = bqkv[o064 + o_loc + 2], b3 = bqkv[o064 + o_loc + 3];
#pragma unroll
      for (int ni = 0; ni < 4; ni++) {
        int t_loc = ni * 16 + (lane & 15);
        s16x4 pk;
        pk[0] = (short)f2bf((acc[mi][ni][0] + b0) * scale);
        pk[1] = (short)f2bf((acc[mi][ni][1] + b1) * scale);
        pk[2] = (short)f2bf((acc[mi][ni][2] + b2) * scale);
        pk[3] = (short)f2bf((acc[mi][ni][3] + b3) * scale);
        *(s16x4*)(tr + t_loc * 128 + ((o_loc * 2) ^ ((t_loc & 7) << 4))) = pk;
      }
    }
    unsigned short* outp = (blk == 0) ? qt : ktb;
#pragma unroll
    for (int pass = 0; pass < 8; pass++) {
      int t = pass * 8 + (lane >> 3);
      int cb = (lane & 7) * 16;
      s16x8 v = *(const s16x8*)(tr + t * 128 + (cb ^ ((t & 7) << 4)));
      *(s16x8*)(outp + (size_t)(bh * NT + n0w + t) * 64 + (cb >> 1)) = v;
    }
  } else {
    // v channel-major [ch][t], C-tile is already row-major in o
#pragma unroll
    for (int mi = 0; mi < 4; mi++) {
#pragma unroll
      for (int ni = 0; ni < 4; ni++) {
        int t_loc = ni * 16 + (lane & 15);
#pragma unroll
        for (int r = 0; r < 4; r++) {
          int o_loc = mi * 16 + (lane >> 4) * 4 + r;
          *(unsigned short*)(tr + o_loc * 128 + t_loc * 2) =
              f2bf(acc[mi][ni][r] + bqkv[o064 + o_loc]);
        }
      }
    }
#pragma unroll
    for (int pass = 0; pass < 8; pass++) {
      int o = pass * 8 + (lane >> 3);
      int tb = (lane & 7) * 16;
      s16x8 v = *(const s16x8*)(tr + o * 128 + tb);
      *(s16x8*)(vvb + (size_t)(bh * 64 + o) * NT + n0w + (tb >> 1)) = v;
    }
  }
}

// ---- kernel 4: flash attention (dbuf K/V + counted vmcnt + raw barriers; MFMA row-sums) ----
__global__ __launch_bounds__(512, 4) void k_attn(const unsigned short* __restrict__ qt,
    const unsigned short* __restrict__ ktb, const unsigned short* __restrict__ vvb,
    unsigned short* __restrict__ rt) {
  __shared__ char Kl[2][8192];        // [64 tk][64 ch] bf16, row-swizzled image, double-buffered
  __shared__ char Vl[2][8192];        // [64 ch][64 tk] bf16, row-swizzled image, double-buffered
  __shared__ char Pl[8][4096];        // per-wave [32 q][64 tk] bf16, row-swizzled
  int qt0 = blockIdx.x * 256;
  int bh = blockIdx.y;
  int b = bh >> 3, head = bh & 7;
  int tid = threadIdx.x, lane = tid & 63, wid = tid >> 6;
  int hi = lane >> 4, lo = lane & 15;
  int q0 = qt0 + wid * 32;
  // Q as B-fragments: aq[mi][ko] = Q[q0+mi*16+lo][ko*32 + hi*8 .. +8]
  s16x8 aq[2][2];
#pragma unroll
  for (int mi = 0; mi < 2; mi++)
#pragma unroll
    for (int ko = 0; ko < 2; ko++)
      aq[mi][ko] = *(const s16x8*)(qt + (size_t)(bh * NT + q0 + mi * 16 + lo) * 64 +
                                   ko * 32 + hi * 8);
  f32x4 oacc[2][4] = {};              // O^T: col q = lo, row d = hi*4+r (per mi, dm)
  f32x4 lacc[2] = {};                 // row-sum accumulator via mfma(ones, P): all rows = l[q]
  float mrun[2] = {-1e30f, -1e30f};
  s16x8 ones;
#pragma unroll
  for (int j = 0; j < 8; j++) ones[j] = (short)0x3F80;   // bf16 1.0
  char* pl = (char*)Pl[wid];
  // async-staging coords: wave wid covers rows wid*8..wid*8+7 (1 KB) of each 8 KB tile;
  // LDS dest linear, swizzle folded into the per-lane GLOBAL address (involution).
  int srow = (wid << 3) + (lane >> 3);
  int soff = ((lane & 7) << 4) ^ ((srow & 7) << 4);
  const char* kb = (const char*)ktb + ((size_t)bh * NT + srow) * 128 + soff;
  const char* vb = (const char*)vvb + ((size_t)(bh * 64 + srow)) * 2048 + soff;
  // prologue: issue tile 0 into buf 0
  __builtin_amdgcn_global_load_lds((const AS1 unsigned int*)kb,
                                   (AS3 unsigned int*)(Kl[0] + (wid << 10)), 16, 0, 0);
  __builtin_amdgcn_global_load_lds((const AS1 unsigned int*)vb,
                                   (AS3 unsigned int*)(Vl[0] + (wid << 10)), 16, 0, 0);
  for (int kv = 0; kv < 16; kv++) {
    int cur = kv & 1;
    if (kv < 15) {
      // prefetch tile kv+1 into the other buffer (its last readers passed the tail barrier)
      __builtin_amdgcn_global_load_lds((const AS1 unsigned int*)(kb + (size_t)(kv + 1) * 8192),
                                       (AS3 unsigned int*)(Kl[cur ^ 1] + (wid << 10)), 16, 0, 0);
      __builtin_amdgcn_global_load_lds((const AS1 unsigned int*)(vb + (size_t)(kv + 1) * 128),
                                       (AS3 unsigned int*)(Vl[cur ^ 1] + (wid << 10)), 16, 0, 0);
      asm volatile("s_waitcnt vmcnt(2)" ::: "memory");   // current tile's 2 loads done
    } else {
      asm volatile("s_waitcnt vmcnt(0)" ::: "memory");
    }
    __builtin_amdgcn_s_barrier();
    __builtin_amdgcn_sched_barrier(0);
    // S^T = K * Q^T : sc[mi][ni] holds S[tk=ni*16+hi*4+r][q=mi*16+lo], exp2 domain
    f32x4 sc[2][4] = {};
#pragma unroll
    for (int ni = 0; ni < 4; ni++) {
      int tkr = ni * 16 + lo;
#pragma unroll
      for (int ko = 0; ko < 2; ko++) {
        s16x8 kf = *(const s16x8*)(Kl[cur] + tkr * 128 + ((ko * 64 + hi * 16) ^ ((tkr & 7) << 4)));
        sc[0][ni] = __builtin_amdgcn_mfma_f32_16x16x32_bf16(kf, aq[0][ko], sc[0][ni], 0, 0, 0);
        sc[1][ni] = __builtin_amdgcn_mfma_f32_16x16x32_bf16(kf, aq[1][ko], sc[1][ni], 0, 0, 0);
      }
    }
    // online softmax (exp2 domain), defer-max (THR=8): per q = lo, + 2 shfl over hi
#pragma unroll
    for (int mi = 0; mi < 2; mi++) {
      float a0 = fmaxf(fmaxf(sc[mi][0][0], sc[mi][0][1]), fmaxf(sc[mi][0][2], sc[mi][0][3]));
      float a1 = fmaxf(fmaxf(sc[mi][1][0], sc[mi][1][1]), fmaxf(sc[mi][1][2], sc[mi][1][3]));
      float a2 = fmaxf(fmaxf(sc[mi][2][0], sc[mi][2][1]), fmaxf(sc[mi][2][2], sc[mi][2][3]));
      float a3 = fmaxf(fmaxf(sc[mi][3][0], sc[mi][3][1]), fmaxf(sc[mi][3][2], sc[mi][3][3]));
      float tm = fmaxf(fmaxf(a0, a1), fmaxf(a2, a3));
      tm = fmaxf(tm, __shfl_xor(tm, 16));
      tm = fmaxf(tm, __shfl_xor(tm, 32));
      int resc = __any(tm > mrun[mi] + 8.f);   // wave-uniform
      float mnew = mrun[mi];
      if (resc) {
        mnew = fmaxf(mrun[mi], tm);
        float fac = exp2_hw(mrun[mi] - mnew);
        mrun[mi] = mnew;
#pragma unroll
        for (int dm = 0; dm < 4; dm++)
#pragma unroll
          for (int r = 0; r < 4; r++) oacc[mi][dm][r] *= fac;
#pragma unroll
        for (int r = 0; r < 4; r++) lacc[mi][r] *= fac;
      }
#pragma unroll
      for (int ni = 0; ni < 4; ni++)
#pragma unroll
        for (int r = 0; r < 4; r++) sc[mi][ni][r] = exp2_hw(sc[mi][ni][r] - mnew);
      // packed P write: 4 consecutive tk per 8B store
      int qrow = mi * 16 + lo;
#pragma unroll
      for (int ni = 0; ni < 4; ni++) {
        u32x2 w;
        w[0] = cvtpk(sc[mi][ni][0], sc[mi][ni][1]);
        w[1] = cvtpk(sc[mi][ni][2], sc[mi][ni][3]);
        *(u32x2*)(pl + (qrow * 128 + ((ni * 32 + hi * 8) ^ ((qrow & 7) << 4)))) = w;
      }
    }
    // PV swapped: O^T[d][q] += V^T[d][tk] * P^T[tk][q]; row-sums via mfma(ones, P)
#pragma unroll
    for (int kt = 0; kt < 2; kt++) {
      s16x8 pa[2];
#pragma unroll
      for (int mi = 0; mi < 2; mi++) {
        int qrow = mi * 16 + lo;
        pa[mi] = *(const s16x8*)(pl + (qrow * 128 + ((kt * 64 + hi * 16) ^ ((qrow & 7) << 4))));
      }
#pragma unroll
      for (int dm = 0; dm < 4; dm++) {
        int dr = dm * 16 + lo;
        s16x8 av = *(const s16x8*)(Vl[cur] + dr * 128 + ((kt * 64 + hi * 16) ^ ((dr & 7) << 4)));
        oacc[0][dm] = __builtin_amdgcn_mfma_f32_16x16x32_bf16(av, pa[0], oacc[0][dm], 0, 0, 0);
        oacc[1][dm] = __builtin_amdgcn_mfma_f32_16x16x32_bf16(av, pa[1], oacc[1][dm], 0, 0, 0);
      }
      lacc[0] = __builtin_amdgcn_mfma_f32_16x16x32_bf16(ones, pa[0], lacc[0], 0, 0, 0);
      lacc[1] = __builtin_amdgcn_mfma_f32_16x16x32_bf16(ones, pa[1], lacc[1], 0, 0, 0);
    }
    // tail barrier: all waves done reading buf[cur^1]-to-be-overwritten & P before next iter
    __builtin_amdgcn_s_barrier();
  }
  // epilogue: O^T -> rt[b*NT+q][head*64+d]; q = lo (lane-local), d = dm*16+hi*4+r
#pragma unroll
  for (int mi = 0; mi < 2; mi++) {
    float inv = 1.f / lacc[mi][0];
    int q = q0 + mi * 16 + lo;
#pragma unroll
    for (int dm = 0; dm < 4; dm++) {
      u32x2 w;
      w[0] = cvtpk(oacc[mi][dm][0] * inv, oacc[mi][dm][1] * inv);
      w[1] = cvtpk(oacc[mi][dm][2] * inv, oacc[mi][dm][3] * inv);
      *(u32x2*)(rt + (size_t)(b * NT + q) * NC + head * 64 + dm * 16 + hi * 4) = w;
    }
  }
}

// -------- kernel 5: out-proj GEMM + bias + residual (triple-buffer, 1 barrier/K-step) --------
__global__ __launch_bounds__(256) void k_proj(const unsigned short* __restrict__ wpb,
    const unsigned short* __restrict__ rt, const float* __restrict__ bproj,
    const float* __restrict__ x, float* __restrict__ out) {
  __shared__ char LB[49152];   // 3 × [A:8K|B:8K]
  int n0 = blockIdx.x * 128;
  int m0 = blockIdx.y * 128;
  int b = blockIdx.z;
  int tid = threadIdx.x, lane = tid & 63, wid = tid >> 6;
  int wr = wid >> 1, wc = wid & 1;
  int arow = lane >> 2, acol = (lane & 3) * 8;
  f32x4 acc[4][4] = {};
#pragma unroll
  for (int t0 = 0; t0 < 2; t0++) {
#pragma unroll
    for (int cc = 0; cc < 2; cc++) {
      int ci = wid * 2 + cc;
      const unsigned short* ga = wpb + (size_t)(m0 + ci * 16 + arow) * NC + t0 * 32 + acol;
      __builtin_amdgcn_global_load_lds((const AS1 unsigned int*)ga,
                                       (AS3 unsigned int*)(LB + t0 * 16384 + ci * 1024), 16, 0, 0);
      const unsigned short* gb = rt + (size_t)(b * NT + n0 + ci * 16 + arow) * NC + t0 * 32 + acol;
      __builtin_amdgcn_global_load_lds((const AS1 unsigned int*)gb,
                                       (AS3 unsigned int*)(LB + t0 * 16384 + 8192 + ci * 1024), 16, 0, 0);
    }
  }
  for (int ks = 0; ks < 16; ks++) {
    char* Ac = LB + (ks % 3) * 16384;
    char* Bc = Ac + 8192;
    if (ks < 14) {
      asm volatile("s_waitcnt vmcnt(4)" ::: "memory");
    } else {
      asm volatile("s_waitcnt vmcnt(0)" ::: "memory");
    }
    __builtin_amdgcn_s_barrier();
    __builtin_amdgcn_sched_barrier(0);
    if (ks + 2 < 16) {
      int k0n = (ks + 2) * 32;
      char* An = LB + ((ks + 2) % 3) * 16384;
#pragma unroll
      for (int cc = 0; cc < 2; cc++) {
        int ci = wid * 2 + cc;
        const unsigned short* ga = wpb + (size_t)(m0 + ci * 16 + arow) * NC + k0n + acol;
        __builtin_amdgcn_global_load_lds((const AS1 unsigned int*)ga,
                                         (AS3 unsigned int*)(An + ci * 1024), 16, 0, 0);
        const unsigned short* gb = rt + (size_t)(b * NT + n0 + ci * 16 + arow) * NC + k0n + acol;
        __builtin_amdgcn_global_load_lds((const AS1 unsigned int*)gb,
                                         (AS3 unsigned int*)(An + 8192 + ci * 1024), 16, 0, 0);
      }
    }
    s16x8 af[4], bfv[4];
#pragma unroll
    for (int mi = 0; mi < 4; mi++)
      af[mi] = *(const s16x8*)(Ac + ((wr * 64 + mi * 16 + (lane & 15)) * 32 + (lane >> 4) * 8) * 2);
#pragma unroll
    for (int ni = 0; ni < 4; ni++)
      bfv[ni] = *(const s16x8*)(Bc + ((wc * 64 + ni * 16 + (lane & 15)) * 32 + (lane >> 4) * 8) * 2);
#pragma unroll
    for (int mi = 0; mi < 4; mi++)
#pragma unroll
      for (int ni = 0; ni < 4; ni++)
        acc[mi][ni] = __builtin_amdgcn_mfma_f32_16x16x32_bf16(af[mi], bfv[ni], acc[mi][ni], 0, 0, 0);
  }
#pragma unroll
  for (int mi = 0; mi < 4; mi++) {
    int o_base = m0 + wr * 64 + mi * 16 + (lane >> 4) * 4;
#pragma unroll
    for (int r = 0; r < 4; r++) {
      int o = o_base + r;
      float bp = bproj[o];
#pragma unroll
      for (int ni = 0; ni < 4; ni++) {
        int t = n0 + wc * 64 + ni * 16 + (lane & 15);
        size_t idx = (size_t)(b * NC + o) * NT + t;
        out[idx] = acc[mi][ni][r] + bp + x[idx];
      }
    }
  }
}

extern "C" void kernel_launch(void* const* d_in, const int* in_sizes, int n_in,
                              void* d_out, int out_size, void* d_ws, size_t ws_size,
                              hipStream_t stream) {
  const float* x   = (const float*)d_in[0];
  const float* gsc = (const float*)d_in[1];
  const float* gbi = (const float*)d_in[2];
  const float* wq  = (const float*)d_in[3];
  const float* bq  = (const float*)d_in[4];
  const float* wp  = (const float*)d_in[5];
  const float* bp  = (const float*)d_in[6];
  float* out = (float*)d_out;
  char* ws = (char*)d_ws;

  unsigned short* wqb = (unsigned short*)(ws + 65536);        // 1536*512 bf16
  unsigned short* wpb = wqb + (size_t)NOC * NC;               // 512*512 bf16
  unsigned short* xt  = (unsigned short*)(ws + 2162688);      // [16][1024][512] bf16
  unsigned short* qt  = xt + (size_t)NB * NT * NC;            // [128][1024][64] bf16 (scaled)
  unsigned short* ktb = qt + (size_t)128 * NT * 64;           // [128][1024][64] bf16 (scaled)
  unsigned short* vvb = ktb + (size_t)128 * NT * 64;          // [128][64][1024] bf16
  unsigned short* rt  = vvb + (size_t)128 * NT * 64;          // [16][1024][512] bf16

  k_convert<<<dim3(1024), 256, 0, stream>>>(wq, wp, wqb, wpb);
  k_gn<<<dim3(512), 256, 0, stream>>>(x, gsc, gbi, xt);
  k_qkv<<<dim3(8, 12, 16), 256, 0, stream>>>(wqb, xt, bq, qt, ktb, vvb);
  k_attn<<<dim3(4, 128), 512, 0, stream>>>(qt, ktb, vvb, rt);
  k_proj<<<dim3(8, 4, 16), 256, 0, stream>>>(wpb, rt, bp, x, out);
}

// Round 23
// 121.159 us; speedup vs baseline: 1.0628x; 1.0266x over previous
//
#include <hip/hip_runtime.h>
#include <stdint.h>
#include <stddef.h>

#define NB 16
#define NC 512
#define NT 1024
#define NHEAD 8
#define NOC 1536

typedef float f32x4 __attribute__((ext_vector_type(4)));
typedef short s16x8 __attribute__((ext_vector_type(8)));
typedef short s16x4 __attribute__((ext_vector_type(4)));
typedef unsigned int u32x2 __attribute__((ext_vector_type(2)));

#define AS1 __attribute__((address_space(1)))
#define AS3 __attribute__((address_space(3)))

static __device__ __forceinline__ unsigned short f2bf(float f) {
  union { float fv; unsigned int u; } v; v.fv = f;
  return (unsigned short)((v.u + 0x7fffu + ((v.u >> 16) & 1u)) >> 16);
}

// v_cvt_pk_bf16_f32: dst.lo16 = bf16(lo), dst.hi16 = bf16(hi)
static __device__ __forceinline__ unsigned int cvtpk(float lo, float hi) {
  unsigned int r;
  asm("v_cvt_pk_bf16_f32 %0, %1, %2" : "=v"(r) : "v"(lo), "v"(hi));
  return r;
}

// v_exp_f32: D = 2^S0 (gfx950 ISA §3) — exp2-domain softmax
static __device__ __forceinline__ float exp2_hw(float x) {
  float r;
  asm("v_exp_f32 %0, %1" : "=v"(r) : "v"(x));
  return r;
}

// ---------------- kernel 0: weights fp32 -> bf16 ----------------
__global__ void k_convert(const float* __restrict__ wq, const float* __restrict__ wp,
                          unsigned short* __restrict__ wqb, unsigned short* __restrict__ wpb) {
  int i = blockIdx.x * 256 + threadIdx.x;
  int step = gridDim.x * 256;
  for (int idx = i; idx < NOC * NC; idx += step) wqb[idx] = f2bf(wq[idx]);
  for (int idx = i; idx < NC * NC; idx += step) wpb[idx] = f2bf(wp[idx]);
}

// ---- kernel 1: FUSED groupnorm (stats + normalize + transpose), single read of x ----
__global__ __launch_bounds__(256) void k_gn(const float* __restrict__ x,
    const float* __restrict__ gsc, const float* __restrict__ gbi,
    unsigned short* __restrict__ xt) {
  __shared__ float xs[16 * 1024];     // [c][t] fp32, 64 KB
  __shared__ float red[4][2];
  __shared__ float mv[2];
  int b = blockIdx.x >> 5, g = blockIdx.x & 31;
  int tid = threadIdx.x;
  const f32x4* p4 = (const f32x4*)(x + (size_t)(b * NC + g * 16) * NT);
  f32x4* s4 = (f32x4*)xs;
  float s = 0.f, ss = 0.f;
  for (int i = tid; i < 4096; i += 256) {
    f32x4 v = p4[i];
    s4[i] = v;
    s += v[0] + v[1] + v[2] + v[3];
    ss += v[0] * v[0] + v[1] * v[1] + v[2] * v[2] + v[3] * v[3];
  }
#pragma unroll
  for (int off = 32; off > 0; off >>= 1) { s += __shfl_down(s, off); ss += __shfl_down(ss, off); }
  if ((tid & 63) == 0) { red[tid >> 6][0] = s; red[tid >> 6][1] = ss; }
  __syncthreads();
  if (tid == 0) {
    float st = red[0][0] + red[1][0] + red[2][0] + red[3][0];
    float sst = red[0][1] + red[1][1] + red[2][1] + red[3][1];
    float mean = st * (1.f / 16384.f);
    float var = sst * (1.f / 16384.f) - mean * mean;
    mv[0] = mean;
    mv[1] = rsqrtf(var + 1e-5f);
  }
  __syncthreads();
  float mean = mv[0], rstd = mv[1];
  int c0 = (tid & 1) * 8;             // thread covers 8 channels; pairs cover one token row
  int cbase = g * 16 + c0;
  float a[8], bb[8];
#pragma unroll
  for (int j = 0; j < 8; j++) {
    a[j] = rstd * gsc[cbase + j];
    bb[j] = gbi[cbase + j] - mean * a[j];
  }
#pragma unroll
  for (int pass = 0; pass < 8; pass++) {
    int t = pass * 128 + (tid >> 1);
    s16x8 o;
#pragma unroll
    for (int j = 0; j < 8; j++)
      o[j] = (short)f2bf(xs[(c0 + j) * 1024 + t] * a[j] + bb[j]);
    *(s16x8*)(xt + (size_t)(b * NT + t) * NC + cbase) = o;
  }
}

// -------- kernel 3: QKV GEMM (triple-buffer, 1 barrier/K-step; Tr aliased post-loop) --------
__global__ __launch_bounds__(256) void k_qkv(const unsigned short* __restrict__ wqb,
    const unsigned short* __restrict__ xt, const float* __restrict__ bqkv,
    unsigned short* __restrict__ qt, unsigned short* __restrict__ ktb,
    unsigned short* __restrict__ vvb) {
  __shared__ char LB[49152];   // 3 × [A:8K|B:8K]; epilogue reuses first 32K as per-wave Tr
  int n0 = blockIdx.x * 128;
  int m0 = blockIdx.y * 128;
  int b = blockIdx.z;
  int tid = threadIdx.x, lane = tid & 63, wid = tid >> 6;
  int wr = wid >> 1, wc = wid & 1;
  int arow = lane >> 2, acol = (lane & 3) * 8;
  f32x4 acc[4][4] = {};
  // prologue: stage ks=0 -> buf0, ks=1 -> buf1
#pragma unroll
  for (int t0 = 0; t0 < 2; t0++) {
#pragma unroll
    for (int cc = 0; cc < 2; cc++) {
      int ci = wid * 2 + cc;
      const unsigned short* ga = wqb + (size_t)(m0 + ci * 16 + arow) * NC + t0 * 32 + acol;
      __builtin_amdgcn_global_load_lds((const AS1 unsigned int*)ga,
                                       (AS3 unsigned int*)(LB + t0 * 16384 + ci * 1024), 16, 0, 0);
      const unsigned short* gb = xt + (size_t)(b * NT + n0 + ci * 16 + arow) * NC + t0 * 32 + acol;
      __builtin_amdgcn_global_load_lds((const AS1 unsigned int*)gb,
                                       (AS3 unsigned int*)(LB + t0 * 16384 + 8192 + ci * 1024), 16, 0, 0);
    }
  }
  for (int ks = 0; ks < 16; ks++) {
    char* Ac = LB + (ks % 3) * 16384;
    char* Bc = Ac + 8192;
    if (ks < 14) {
      asm volatile("s_waitcnt vmcnt(4)" ::: "memory");   // tile ks landed (ks+1 in flight)
    } else {
      asm volatile("s_waitcnt vmcnt(0)" ::: "memory");
    }
    __builtin_amdgcn_s_barrier();
    __builtin_amdgcn_sched_barrier(0);
    if (ks + 2 < 16) {
      // prefetch tile ks+2 into buf[(ks+2)%3] — its last readers passed the barrier above
      int k0n = (ks + 2) * 32;
      char* An = LB + ((ks + 2) % 3) * 16384;
#pragma unroll
      for (int cc = 0; cc < 2; cc++) {
        int ci = wid * 2 + cc;
        const unsigned short* ga = wqb + (size_t)(m0 + ci * 16 + arow) * NC + k0n + acol;
        __builtin_amdgcn_global_load_lds((const AS1 unsigned int*)ga,
                                         (AS3 unsigned int*)(An + ci * 1024), 16, 0, 0);
        const unsigned short* gb = xt + (size_t)(b * NT + n0 + ci * 16 + arow) * NC + k0n + acol;
        __builtin_amdgcn_global_load_lds((const AS1 unsigned int*)gb,
                                         (AS3 unsigned int*)(An + 8192 + ci * 1024), 16, 0, 0);
      }
    }
    s16x8 af[4], bfv[4];
#pragma unroll
    for (int mi = 0; mi < 4; mi++)
      af[mi] = *(const s16x8*)(Ac + ((wr * 64 + mi * 16 + (lane & 15)) * 32 + (lane >> 4) * 8) * 2);
#pragma unroll
    for (int ni = 0; ni < 4; ni++)
      bfv[ni] = *(const s16x8*)(Bc + ((wc * 64 + ni * 16 + (lane & 15)) * 32 + (lane >> 4) * 8) * 2);
#pragma unroll
    for (int mi = 0; mi < 4; mi++)
#pragma unroll
      for (int ni = 0; ni < 4; ni++)
        acc[mi][ni] = __builtin_amdgcn_mfma_f32_16x16x32_bf16(af[mi], bfv[ni], acc[mi][ni], 0, 0, 0);
  }
  __syncthreads();   // all waves done with LDS buffers before Tr aliasing
  // epilogue: per-wave private Tr region aliased onto the dead buffers
  char* tr = LB + wid * 8192;
  int o064 = m0 + wr * 64;
  int blk = (o064 >> 6) % 3;  // 0=q 1=k 2=v
  int head = o064 / 192;
  int bh = b * NHEAD + head;
  int n0w = n0 + wc * 64;
  // 64^-0.25 * sqrt(log2(e)) folded into q and k (softmax runs in exp2 domain)
  const float scale = 0.42466090014400953f;
  if (blk < 2) {
    // token-major [t][ch] via swizzled LDS transpose
#pragma unroll
    for (int mi = 0; mi < 4; mi++) {
      int o_loc = mi * 16 + (lane >> 4) * 4;
      float b0 = bqkv[o064 + o_loc + 0], b1 = bqkv[o064 + o_loc + 1];
      float b2 = bqkv[o064 + o_loc + 2], b3 = bqkv[o064 + o_loc + 3];
#pragma unroll
      for (int ni = 0; ni < 4; ni++) {
        int t_loc = ni * 16 + (lane & 15);
        s16x4 pk;
        pk[0] = (short)f2bf((acc[mi][ni][0] + b0) * scale);
        pk[1] = (short)f2bf((acc[mi][ni][1] + b1) * scale);
        pk[2] = (short)f2bf((acc[mi][ni][2] + b2) * scale);
        pk[3] = (short)f2bf((acc[mi][ni][3] + b3) * scale);
        *(s16x4*)(tr + t_loc * 128 + ((o_loc * 2) ^ ((t_loc & 7) << 4))) = pk;
      }
    }
    unsigned short* outp = (blk == 0) ? qt : ktb;
#pragma unroll
    for (int pass = 0; pass < 8; pass++) {
      int t = pass * 8 + (lane >> 3);
      int cb = (lane & 7) * 16;
      s16x8 v = *(const s16x8*)(tr + t * 128 + (cb ^ ((t & 7) << 4)));
      *(s16x8*)(outp + (size_t)(bh * NT + n0w + t) * 64 + (cb >> 1)) = v;
    }
  } else {
    // v channel-major [ch][t], C-tile is already row-major in o
#pragma unroll
    for (int mi = 0; mi < 4; mi++) {
#pragma unroll
      for (int ni = 0; ni < 4; ni++) {
        int t_loc = ni * 16 + (lane & 15);
#pragma unroll
        for (int r = 0; r < 4; r++) {
          int o_loc = mi * 16 + (lane >> 4) * 4 + r;
          *(unsigned short*)(tr + o_loc * 128 + t_loc * 2) =
              f2bf(acc[mi][ni][r] + bqkv[o064 + o_loc]);
        }
      }
    }
#pragma unroll
    for (int pass = 0; pass < 8; pass++) {
      int o = pass * 8 + (lane >> 3);
      int tb = (lane & 7) * 16;
      s16x8 v = *(const s16x8*)(tr + o * 128 + tb);
      *(s16x8*)(vvb + (size_t)(bh * 64 + o) * NT + n0w + (tb >> 1)) = v;
    }
  }
}

// ---- kernel 4: flash attention (triple-buffer, FULLY UNROLLED kv loop: static LDS
//      addresses, 1 barrier/iter, prefetch in r19 position (before wait+barrier)) ----
__global__ __launch_bounds__(512, 4) void k_attn(const unsigned short* __restrict__ qt,
    const unsigned short* __restrict__ ktb, const unsigned short* __restrict__ vvb,
    unsigned short* __restrict__ rt) {
  __shared__ char Kl[3][8192];        // [64 tk][64 ch] bf16, row-swizzled image
  __shared__ char Vl[3][8192];        // [64 ch][64 tk] bf16, row-swizzled image
  __shared__ char Pl[8][4096];        // per-wave [32 q][64 tk] bf16, row-swizzled
  int qt0 = blockIdx.x * 256;
  int bh = blockIdx.y;
  int b = bh >> 3, head = bh & 7;
  int tid = threadIdx.x, lane = tid & 63, wid = tid >> 6;
  int hi = lane >> 4, lo = lane & 15;
  int q0 = qt0 + wid * 32;
  // Q as B-fragments: aq[mi][ko] = Q[q0+mi*16+lo][ko*32 + hi*8 .. +8]
  s16x8 aq[2][2];
#pragma unroll
  for (int mi = 0; mi < 2; mi++)
#pragma unroll
    for (int ko = 0; ko < 2; ko++)
      aq[mi][ko] = *(const s16x8*)(qt + (size_t)(bh * NT + q0 + mi * 16 + lo) * 64 +
                                   ko * 32 + hi * 8);
  f32x4 oacc[2][4] = {};              // O^T: col q = lo, row d = hi*4+r (per mi, dm)
  f32x4 lacc[2] = {};                 // row-sum accumulator via mfma(ones, P)
  float mrun[2] = {-1e30f, -1e30f};
  s16x8 ones;
#pragma unroll
  for (int j = 0; j < 8; j++) ones[j] = (short)0x3F80;   // bf16 1.0
  char* pl = (char*)Pl[wid];
  // async-staging coords: wave wid covers rows wid*8..wid*8+7 (1 KB) of each 8 KB tile;
  // LDS dest linear, swizzle folded into the per-lane GLOBAL address (involution).
  int srow = (wid << 3) + (lane >> 3);
  int soff = ((lane & 7) << 4) ^ ((srow & 7) << 4);
  const char* kb = (const char*)ktb + ((size_t)bh * NT + srow) * 128 + soff;
  const char* vb = (const char*)vvb + ((size_t)(bh * 64 + srow)) * 2048 + soff;
  // prologue: issue tile 0 into buf 0 (steady state: exactly 2 tiles in flight)
  __builtin_amdgcn_global_load_lds((const AS1 unsigned int*)kb,
                                   (AS3 unsigned int*)(Kl[0] + (wid << 10)), 16, 0, 0);
  __builtin_amdgcn_global_load_lds((const AS1 unsigned int*)vb,
                                   (AS3 unsigned int*)(Vl[0] + (wid << 10)), 16, 0, 0);
#pragma unroll
  for (int kv = 0; kv < 16; kv++) {
    const int cur = kv % 3;           // compile-time constant under full unroll
    if (kv + 1 < 16) {
      // prefetch kv+1 into buf[(kv+1)%3]: its last readers (iter kv-2) are past the
      // kv-1 head barrier, which every wave passed before any wave reached here.
      const int nb = (kv + 1) % 3;
      __builtin_amdgcn_global_load_lds((const AS1 unsigned int*)(kb + (size_t)(kv + 1) * 8192),
                                       (AS3 unsigned int*)(Kl[nb] + (wid << 10)), 16, 0, 0);
      __builtin_amdgcn_global_load_lds((const AS1 unsigned int*)(vb + (size_t)(kv + 1) * 128),
                                       (AS3 unsigned int*)(Vl[nb] + (wid << 10)), 16, 0, 0);
      asm volatile("s_waitcnt vmcnt(2)" ::: "memory");   // current tile's 2 loads done
    } else {
      asm volatile("s_waitcnt vmcnt(0)" ::: "memory");
    }
    __builtin_amdgcn_s_barrier();
    __builtin_amdgcn_sched_barrier(0);
    // S^T = K * Q^T : sc[mi][ni] holds S[tk=ni*16+hi*4+r][q=mi*16+lo], exp2 domain
    f32x4 sc[2][4] = {};
#pragma unroll
    for (int ni = 0; ni < 4; ni++) {
      int tkr = ni * 16 + lo;
#pragma unroll
      for (int ko = 0; ko < 2; ko++) {
        s16x8 kf = *(const s16x8*)(Kl[cur] + tkr * 128 + ((ko * 64 + hi * 16) ^ ((tkr & 7) << 4)));
        sc[0][ni] = __builtin_amdgcn_mfma_f32_16x16x32_bf16(kf, aq[0][ko], sc[0][ni], 0, 0, 0);
        sc[1][ni] = __builtin_amdgcn_mfma_f32_16x16x32_bf16(kf, aq[1][ko], sc[1][ni], 0, 0, 0);
      }
    }
    // online softmax (exp2 domain), defer-max (THR=8): per q = lo, + 2 shfl over hi
#pragma unroll
    for (int mi = 0; mi < 2; mi++) {
      float a0 = fmaxf(fmaxf(sc[mi][0][0], sc[mi][0][1]), fmaxf(sc[mi][0][2], sc[mi][0][3]));
      float a1 = fmaxf(fmaxf(sc[mi][1][0], sc[mi][1][1]), fmaxf(sc[mi][1][2], sc[mi][1][3]));
      float a2 = fmaxf(fmaxf(sc[mi][2][0], sc[mi][2][1]), fmaxf(sc[mi][2][2], sc[mi][2][3]));
      float a3 = fmaxf(fmaxf(sc[mi][3][0], sc[mi][3][1]), fmaxf(sc[mi][3][2], sc[mi][3][3]));
      float tm = fmaxf(fmaxf(a0, a1), fmaxf(a2, a3));
      tm = fmaxf(tm, __shfl_xor(tm, 16));
      tm = fmaxf(tm, __shfl_xor(tm, 32));
      int resc = __any(tm > mrun[mi] + 8.f);   // wave-uniform
      float mnew = mrun[mi];
      if (resc) {
        mnew = fmaxf(mrun[mi], tm);
        float fac = exp2_hw(mrun[mi] - mnew);
        mrun[mi] = mnew;
#pragma unroll
        for (int dm = 0; dm < 4; dm++)
#pragma unroll
          for (int r = 0; r < 4; r++) oacc[mi][dm][r] *= fac;
#pragma unroll
        for (int r = 0; r < 4; r++) lacc[mi][r] *= fac;
      }
#pragma unroll
      for (int ni = 0; ni < 4; ni++)
#pragma unroll
        for (int r = 0; r < 4; r++) sc[mi][ni][r] = exp2_hw(sc[mi][ni][r] - mnew);
      // packed P write: 4 consecutive tk per 8B store
      int qrow = mi * 16 + lo;
#pragma unroll
      for (int ni = 0; ni < 4; ni++) {
        u32x2 w;
        w[0] = cvtpk(sc[mi][ni][0], sc[mi][ni][1]);
        w[1] = cvtpk(sc[mi][ni][2], sc[mi][ni][3]);
        *(u32x2*)(pl + (qrow * 128 + ((ni * 32 + hi * 8) ^ ((qrow & 7) << 4)))) = w;
      }
    }
    // PV swapped: O^T[d][q] += V^T[d][tk] * P^T[tk][q]; row-sums via mfma(ones, P)
#pragma unroll
    for (int kt = 0; kt < 2; kt++) {
      s16x8 pa[2];
#pragma unroll
      for (int mi = 0; mi < 2; mi++) {
        int qrow = mi * 16 + lo;
        pa[mi] = *(const s16x8*)(pl + (qrow * 128 + ((kt * 64 + hi * 16) ^ ((qrow & 7) << 4))));
      }
#pragma unroll
      for (int dm = 0; dm < 4; dm++) {
        int dr = dm * 16 + lo;
        s16x8 av = *(const s16x8*)(Vl[cur] + dr * 128 + ((kt * 64 + hi * 16) ^ ((dr & 7) << 4)));
        oacc[0][dm] = __builtin_amdgcn_mfma_f32_16x16x32_bf16(av, pa[0], oacc[0][dm], 0, 0, 0);
        oacc[1][dm] = __builtin_amdgcn_mfma_f32_16x16x32_bf16(av, pa[1], oacc[1][dm], 0, 0, 0);
      }
      lacc[0] = __builtin_amdgcn_mfma_f32_16x16x32_bf16(ones, pa[0], lacc[0], 0, 0, 0);
      lacc[1] = __builtin_amdgcn_mfma_f32_16x16x32_bf16(ones, pa[1], lacc[1], 0, 0, 0);
    }
    // no tail barrier: triple-buffer rotation bounds drift to one iteration
  }
  // epilogue: O^T -> rt[b*NT+q][head*64+d]; q = lo (lane-local), d = dm*16+hi*4+r
#pragma unroll
  for (int mi = 0; mi < 2; mi++) {
    float inv = 1.f / lacc[mi][0];
    int q = q0 + mi * 16 + lo;
#pragma unroll
    for (int dm = 0; dm < 4; dm++) {
      u32x2 w;
      w[0] = cvtpk(oacc[mi][dm][0] * inv, oacc[mi][dm][1] * inv);
      w[1] = cvtpk(oacc[mi][dm][2] * inv, oacc[mi][dm][3] * inv);
      *(u32x2*)(rt + (size_t)(b * NT + q) * NC + head * 64 + dm * 16 + hi * 4) = w;
    }
  }
}

// -------- kernel 5: out-proj GEMM + bias + residual (triple-buffer, 1 barrier/K-step) --------
__global__ __launch_bounds__(256) void k_proj(const unsigned short* __restrict__ wpb,
    const unsigned short* __restrict__ rt, const float* __restrict__ bproj,
    const float* __restrict__ x, float* __restrict__ out) {
  __shared__ char LB[49152];   // 3 × [A:8K|B:8K]
  int n0 = blockIdx.x * 128;
  int m0 = blockIdx.y * 128;
  int b = blockIdx.z;
  int tid = threadIdx.x, lane = tid & 63, wid = tid >> 6;
  int wr = wid >> 1, wc = wid & 1;
  int arow = lane >> 2, acol = (lane & 3) * 8;
  f32x4 acc[4][4] = {};
#pragma unroll
  for (int t0 = 0; t0 < 2; t0++) {
#pragma unroll
    for (int cc = 0; cc < 2; cc++) {
      int ci = wid * 2 + cc;
      const unsigned short* ga = wpb + (size_t)(m0 + ci * 16 + arow) * NC + t0 * 32 + acol;
      __builtin_amdgcn_global_load_lds((const AS1 unsigned int*)ga,
                                       (AS3 unsigned int*)(LB + t0 * 16384 + ci * 1024), 16, 0, 0);
      const unsigned short* gb = rt + (size_t)(b * NT + n0 + ci * 16 + arow) * NC + t0 * 32 + acol;
      __builtin_amdgcn_global_load_lds((const AS1 unsigned int*)gb,
                                       (AS3 unsigned int*)(LB + t0 * 16384 + 8192 + ci * 1024), 16, 0, 0);
    }
  }
  for (int ks = 0; ks < 16; ks++) {
    char* Ac = LB + (ks % 3) * 16384;
    char* Bc = Ac + 8192;
    if (ks < 14) {
      asm volatile("s_waitcnt vmcnt(4)" ::: "memory");
    } else {
      asm volatile("s_waitcnt vmcnt(0)" ::: "memory");
    }
    __builtin_amdgcn_s_barrier();
    __builtin_amdgcn_sched_barrier(0);
    if (ks + 2 < 16) {
      int k0n = (ks + 2) * 32;
      char* An = LB + ((ks + 2) % 3) * 16384;
#pragma unroll
      for (int cc = 0; cc < 2; cc++) {
        int ci = wid * 2 + cc;
        const unsigned short* ga = wpb + (size_t)(m0 + ci * 16 + arow) * NC + k0n + acol;
        __builtin_amdgcn_global_load_lds((const AS1 unsigned int*)ga,
                                         (AS3 unsigned int*)(An + ci * 1024), 16, 0, 0);
        const unsigned short* gb = rt + (size_t)(b * NT + n0 + ci * 16 + arow) * NC + k0n + acol;
        __builtin_amdgcn_global_load_lds((const AS1 unsigned int*)gb,
                                         (AS3 unsigned int*)(An + 8192 + ci * 1024), 16, 0, 0);
      }
    }
    s16x8 af[4], bfv[4];
#pragma unroll
    for (int mi = 0; mi < 4; mi++)
      af[mi] = *(const s16x8*)(Ac + ((wr * 64 + mi * 16 + (lane & 15)) * 32 + (lane >> 4) * 8) * 2);
#pragma unroll
    for (int ni = 0; ni < 4; ni++)
      bfv[ni] = *(const s16x8*)(Bc + ((wc * 64 + ni * 16 + (lane & 15)) * 32 + (lane >> 4) * 8) * 2);
#pragma unroll
    for (int mi = 0; mi < 4; mi++)
#pragma unroll
      for (int ni = 0; ni < 4; ni++)
        acc[mi][ni] = __builtin_amdgcn_mfma_f32_16x16x32_bf16(af[mi], bfv[ni], acc[mi][ni], 0, 0, 0);
  }
#pragma unroll
  for (int mi = 0; mi < 4; mi++) {
    int o_base = m0 + wr * 64 + mi * 16 + (lane >> 4) * 4;
#pragma unroll
    for (int r = 0; r < 4; r++) {
      int o = o_base + r;
      float bp = bproj[o];
#pragma unroll
      for (int ni = 0; ni < 4; ni++) {
        int t = n0 + wc * 64 + ni * 16 + (lane & 15);
        size_t idx = (size_t)(b * NC + o) * NT + t;
        out[idx] = acc[mi][ni][r] + bp + x[idx];
      }
    }
  }
}

extern "C" void kernel_launch(void* const* d_in, const int* in_sizes, int n_in,
                              void* d_out, int out_size, void* d_ws, size_t ws_size,
                              hipStream_t stream) {
  const float* x   = (const float*)d_in[0];
  const float* gsc = (const float*)d_in[1];
  const float* gbi = (const float*)d_in[2];
  const float* wq  = (const float*)d_in[3];
  const float* bq  = (const float*)d_in[4];
  const float* wp  = (const float*)d_in[5];
  const float* bp  = (const float*)d_in[6];
  float* out = (float*)d_out;
  char* ws = (char*)d_ws;

  unsigned short* wqb = (unsigned short*)(ws + 65536);        // 1536*512 bf16
  unsigned short* wpb = wqb + (size_t)NOC * NC;               // 512*512 bf16
  unsigned short* xt  = (unsigned short*)(ws + 2162688);      // [16][1024][512] bf16
  unsigned short* qt  = xt + (size_t)NB * NT * NC;            // [128][1024][64] bf16 (scaled)
  unsigned short* ktb = qt + (size_t)128 * NT * 64;           // [128][1024][64] bf16 (scaled)
  unsigned short* vvb = ktb + (size_t)128 * NT * 64;          // [128][64][1024] bf16
  unsigned short* rt  = vvb + (size_t)128 * NT * 64;          // [16][1024][512] bf16

  k_convert<<<dim3(1024), 256, 0, stream>>>(wq, wp, wqb, wpb);
  k_gn<<<dim3(512), 256, 0, stream>>>(x, gsc, gbi, xt);
  k_qkv<<<dim3(8, 12, 16), 256, 0, stream>>>(wqb, xt, bq, qt, ktb, vvb);
  k_attn<<<dim3(4, 128), 512, 0, stream>>>(qt, ktb, vvb, rt);
  k_proj<<<dim3(8, 4, 16), 256, 0, stream>>>(wpb, rt, bp, x, out);
}